// Round 1
// baseline (1399.841 us; speedup 1.0000x reference)
//
#include <hip/hip_runtime.h>
#include <math.h>

// Problem constants
#define NB   216        // kept bins
#define W1   432        // transform width = conv1 width
#define W2   405        // conv2 output width
#define NSAMP 4096
#define NFFTC 1747

// ws layout (in floats):
//  region A (Y then H2): max(32768*432, 4096*16*405) = 26,542,080 floats
//  C1: 4096*16*432 = 28,311,552 floats
//  basis (padded to 448 cols): 448*512 = 229,376 floats
//  stats raw: 64 floats ; finalized scale/shift: 64 floats
#define AREG   26542080
#define C1SZ   28311552
#define BASSZ  (448*512)

// ---------------------------------------------------------------- basis table
__global__ void k_basis(float* __restrict__ bas) {
    int idx = blockIdx.x * 256 + threadIdx.x;   // 448*512 total
    int w = idx >> 9, t = idx & 511;
    float v = 0.f;
    if (w < W1) {
        int k = (w < NB) ? (24 + w) : (w - 192);      // 24..239
        int m = (k * t) % NFFTC;                       // exact
        float ang = (float)m * (float)(6.283185307179586 / 1747.0);
        float c = (w < NB) ? cosf(ang) : -sinf(ang);   // rfft: Re=+cos, Im=-sin
        v = c * (1.f / 512.f);
    }
    bas[idx] = v;
}

// ---------------------------------------------------------------- DFT as GEMM
// Y[32768,432] = X[32768,512] @ Basis^T ; tiles 128x64, thread 8x4
__global__ __launch_bounds__(256) void k_dft(const float* __restrict__ xg,
                                             const float* __restrict__ bas,
                                             float* __restrict__ Y) {
    __shared__ float As[32][129];
    __shared__ float Bs[32][65];
    int nt = blockIdx.x;              // 0..6
    int mt = blockIdx.y;              // 0..255
    int tid = threadIdx.x;
    int rowbase = mt * 128, colbase = nt * 64;
    int tx = tid & 15, ty = tid >> 4;
    float acc[8][4] = {};
    for (int k0 = 0; k0 < 512; k0 += 32) {
        #pragma unroll
        for (int i = 0; i < 16; ++i) {
            int idx = i * 256 + tid;
            int m = idx >> 5, kk = idx & 31;
            As[kk][m] = xg[(rowbase + m) * 512 + k0 + kk];
        }
        #pragma unroll
        for (int i = 0; i < 8; ++i) {
            int idx = i * 256 + tid;
            int w = idx >> 5, kk = idx & 31;
            Bs[kk][w] = bas[(colbase + w) * 512 + k0 + kk];
        }
        __syncthreads();
        #pragma unroll
        for (int kk = 0; kk < 32; ++kk) {
            float a[8], b[4];
            #pragma unroll
            for (int i = 0; i < 8; ++i) a[i] = As[kk][ty * 8 + i];
            #pragma unroll
            for (int j = 0; j < 4; ++j) b[j] = Bs[kk][tx * 4 + j];
            #pragma unroll
            for (int i = 0; i < 8; ++i)
                #pragma unroll
                for (int j = 0; j < 4; ++j)
                    acc[i][j] = fmaf(a[i], b[j], acc[i][j]);
        }
        __syncthreads();
    }
    #pragma unroll
    for (int i = 0; i < 8; ++i) {
        int r = rowbase + ty * 8 + i;
        #pragma unroll
        for (int j = 0; j < 4; ++j) {
            int w = colbase + tx * 4 + j;
            if (w < W1) Y[r * W1 + w] = acc[i][j];
        }
    }
}

// ------------------------------------------------- conv1 (+att1, + BN1 stats)
__global__ __launch_bounds__(256) void k_conv1(const float* __restrict__ Y,
        const float* __restrict__ w1k, const float* __restrict__ a1w1,
        const float* __restrict__ a1b1, const float* __restrict__ a1w2,
        const float* __restrict__ a1b2,
        float* __restrict__ C1, float* __restrict__ stats) {
    __shared__ float Ys[8 * W1];
    __shared__ float kers[128];
    __shared__ float red[4];
    int b = blockIdx.x, tid = threadIdx.x;
    const float* yb = Y + b * (8 * W1);
    float psum = 0.f;
    for (int idx = tid; idx < 8 * W1; idx += 256) {
        float v = yb[idx]; Ys[idx] = v; psum += v;
    }
    #pragma unroll
    for (int m = 32; m; m >>= 1) psum += __shfl_xor(psum, m);
    if ((tid & 63) == 0) red[tid >> 6] = psum;
    __syncthreads();
    float p1 = (red[0] + red[1] + red[2] + red[3]) * (1.f / (8.f * W1));
    float h = fmaxf(p1 * a1w1[0] + a1b1[0], 0.f);
    float l[4], mx = -1e30f;
    #pragma unroll
    for (int k = 0; k < 4; ++k) { l[k] = (h * a1w2[k] + a1b2[k]) * (1.f / 30.f); mx = fmaxf(mx, l[k]); }
    float es = 0.f;
    #pragma unroll
    for (int k = 0; k < 4; ++k) { l[k] = expf(l[k] - mx); es += l[k]; }
    float inv = 1.f / es;
    if (tid < 128) {   // o = tid>>3, hh = tid&7 -> w1k[k*128 + tid]
        float kv = 0.f;
        #pragma unroll
        for (int k = 0; k < 4; ++k) kv += l[k] * inv * w1k[k * 128 + tid];
        kers[tid] = kv;
    }
    __syncthreads();
    int o = tid >> 4, wl = tid & 15;
    float kr[8];
    #pragma unroll
    for (int hh = 0; hh < 8; ++hh) kr[hh] = kers[o * 8 + hh];
    float ssum = 0.f, ssq = 0.f;
    float* c1b = C1 + (b * 16 + o) * W1;
    #pragma unroll 3
    for (int j = 0; j < 27; ++j) {
        int w = wl + 16 * j;
        float acc = 0.f;
        #pragma unroll
        for (int hh = 0; hh < 8; ++hh) acc = fmaf(kr[hh], Ys[hh * W1 + w], acc);
        c1b[w] = acc;
        ssum += acc; ssq = fmaf(acc, acc, ssq);
    }
    #pragma unroll
    for (int m = 1; m < 16; m <<= 1) { ssum += __shfl_xor(ssum, m); ssq += __shfl_xor(ssq, m); }
    if (wl == 0) { atomicAdd(&stats[o], ssum); atomicAdd(&stats[16 + o], ssq); }
}

// ------------------------------------------------------------- stats finalize
__global__ void k_statfin(const float* __restrict__ stats, const float* __restrict__ g,
                          const float* __restrict__ bb, float* __restrict__ ss, float cnt) {
    int i = threadIdx.x;
    if (i < 16) {
        float mean = stats[i] / cnt;
        float var  = stats[16 + i] / cnt - mean * mean;
        float istd = rsqrtf(var + 1e-5f);
        float sc = g[i] * istd;
        ss[i] = sc;
        ss[16 + i] = bb[i] - mean * sc;
    }
}

// ---------------------------------- conv2 (applies BN1+relu, +att2, BN2 stats)
__global__ __launch_bounds__(256) void k_conv2(const float* __restrict__ C1,
        const float* __restrict__ w2k, const float* __restrict__ a2w1,
        const float* __restrict__ a2b1, const float* __restrict__ a2w2,
        const float* __restrict__ a2b2, const float* __restrict__ ss,
        float* __restrict__ H2, float* __restrict__ stats2) {
    __shared__ float H1s[16 * W1];
    __shared__ float ker2[2560];
    __shared__ float p2s[16];
    int b = blockIdx.x, tid = threadIdx.x;
    int o = tid >> 4, wl = tid & 15;
    float sc = ss[o], sh = ss[16 + o];
    const float* cb = C1 + (b * 16 + o) * W1;
    float ps = 0.f;
    #pragma unroll 3
    for (int j = 0; j < 27; ++j) {
        int w = wl + 16 * j;
        float v = fmaxf(fmaf(cb[w], sc, sh), 0.f);   // BN1 + relu applied lazily
        H1s[o * W1 + w] = v;
        ps += v;
    }
    #pragma unroll
    for (int m = 1; m < 16; m <<= 1) ps += __shfl_xor(ps, m);
    if (wl == 0) p2s[o] = ps * (1.f / W1);
    __syncthreads();
    // att2 (redundant per-thread, cheap)
    float hv[4];
    #pragma unroll
    for (int j = 0; j < 4; ++j) {
        float a = a2b1[j];
        #pragma unroll
        for (int i = 0; i < 16; ++i) a = fmaf(a2w1[j * 16 + i], p2s[i], a);
        hv[j] = fmaxf(a, 0.f);
    }
    float l[4], mx = -1e30f;
    #pragma unroll
    for (int k = 0; k < 4; ++k) {
        float a = a2b2[k];
        #pragma unroll
        for (int j = 0; j < 4; ++j) a = fmaf(a2w2[k * 4 + j], hv[j], a);
        l[k] = a * (1.f / 30.f); mx = fmaxf(mx, l[k]);
    }
    float es = 0.f;
    #pragma unroll
    for (int k = 0; k < 4; ++k) { l[k] = expf(l[k] - mx); es += l[k]; }
    float inv = 1.f / es;
    float at0 = l[0] * inv, at1 = l[1] * inv, at2 = l[2] * inv, at3 = l[3] * inv;
    for (int idx = tid; idx < 2560; idx += 256)
        ker2[idx] = at0 * w2k[idx] + at1 * w2k[2560 + idx] + at2 * w2k[5120 + idx] + at3 * w2k[7680 + idx];
    __syncthreads();
    // conv: each thread: 4 output channels (og*4+q) x 7 w-slots (lane + 64j)
    int lane = tid & 63, og = tid >> 6;
    int   wb[7]; bool wv[7];
    #pragma unroll
    for (int j = 0; j < 7; ++j) { int w = lane + 64 * j; wv[j] = (w < W2); wb[j] = wv[j] ? w : (W2 - 1); }
    float acc[7][4] = {};
    for (int i = 0; i < 16; ++i) {
        const float* hrow = H1s + i * W1;
        const float* krow = ker2 + i * 10;
        #pragma unroll
        for (int tp = 0; tp < 10; ++tp) {
            float kv[4];
            #pragma unroll
            for (int q = 0; q < 4; ++q) kv[q] = krow[(og * 4 + q) * 160 + tp];
            #pragma unroll
            for (int j = 0; j < 7; ++j) {
                float hvv = hrow[wb[j] + 3 * tp];
                #pragma unroll
                for (int q = 0; q < 4; ++q) acc[j][q] = fmaf(kv[q], hvv, acc[j][q]);
            }
        }
    }
    float s2[4] = {}, q2[4] = {};
    #pragma unroll
    for (int j = 0; j < 7; ++j) {
        if (wv[j]) {
            #pragma unroll
            for (int q = 0; q < 4; ++q) {
                float v = acc[j][q];
                H2[((b * 16 + og * 4 + q) * W2) + lane + 64 * j] = v;
                s2[q] += v; q2[q] = fmaf(v, v, q2[q]);
            }
        }
    }
    #pragma unroll
    for (int m = 1; m < 64; m <<= 1) {
        #pragma unroll
        for (int q = 0; q < 4; ++q) { s2[q] += __shfl_xor(s2[q], m); q2[q] += __shfl_xor(q2[q], m); }
    }
    if (lane == 0) {
        #pragma unroll
        for (int q = 0; q < 4; ++q) {
            atomicAdd(&stats2[og * 4 + q], s2[q]);
            atomicAdd(&stats2[16 + og * 4 + q], q2[q]);
        }
    }
}

// ------------------------------------------------------------ BN2+relu+FC out
__global__ __launch_bounds__(256) void k_fc(const float* __restrict__ H2,
        const float* __restrict__ ss2, const float* __restrict__ fcw,
        const float* __restrict__ fcb, float* __restrict__ out) {
    __shared__ float red[4][4];
    int b = blockIdx.x, tid = threadIdx.x;
    const float* hb = H2 + b * (16 * W2);
    float acc[4] = {};
    for (int idx = tid; idx < 16 * W2; idx += 256) {
        int o = idx / W2;
        float v = fmaxf(fmaf(hb[idx], ss2[o], ss2[16 + o]), 0.f);
        #pragma unroll
        for (int n = 0; n < 4; ++n) acc[n] = fmaf(v, fcw[n * (16 * W2) + idx], acc[n]);
    }
    #pragma unroll
    for (int m = 1; m < 64; m <<= 1)
        #pragma unroll
        for (int n = 0; n < 4; ++n) acc[n] += __shfl_xor(acc[n], m);
    int wid = tid >> 6, lane = tid & 63;
    if (lane == 0) {
        #pragma unroll
        for (int n = 0; n < 4; ++n) red[wid][n] = acc[n];
    }
    __syncthreads();
    if (tid < 4)
        out[b * 4 + tid] = red[0][tid] + red[1][tid] + red[2][tid] + red[3][tid] + fcb[tid];
}

extern "C" void kernel_launch(void* const* d_in, const int* in_sizes, int n_in,
                              void* d_out, int out_size, void* d_ws, size_t ws_size,
                              hipStream_t stream) {
    const float* x    = (const float*)d_in[0];
    const float* w1k  = (const float*)d_in[1];
    const float* a1w1 = (const float*)d_in[2];
    const float* a1b1 = (const float*)d_in[3];
    const float* a1w2 = (const float*)d_in[4];
    const float* a1b2 = (const float*)d_in[5];
    const float* g1   = (const float*)d_in[6];
    const float* b1   = (const float*)d_in[7];
    const float* w2k  = (const float*)d_in[8];
    const float* a2w1 = (const float*)d_in[9];
    const float* a2b1 = (const float*)d_in[10];
    const float* a2w2 = (const float*)d_in[11];
    const float* a2b2 = (const float*)d_in[12];
    const float* g2   = (const float*)d_in[13];
    const float* b2   = (const float*)d_in[14];
    const float* fcw  = (const float*)d_in[15];
    const float* fcb  = (const float*)d_in[16];

    float* ws   = (float*)d_ws;
    float* Y    = ws;                 // region A (dead after conv1)
    float* H2   = ws;                 // region A reused
    float* C1   = ws + AREG;
    float* bas  = ws + AREG + C1SZ;
    float* stats = bas + BASSZ;       // raw: [s1sum16][s1sq16][s2sum16][s2sq16]
    float* ssf   = stats + 64;        // finalized: [sc1 16][sh1 16][sc2 16][sh2 16]

    hipMemsetAsync(stats, 0, 64 * sizeof(float), stream);
    k_basis<<<BASSZ / 256, 256, 0, stream>>>(bas);
    k_dft<<<dim3(7, 256), 256, 0, stream>>>(x, bas, Y);
    k_conv1<<<NSAMP, 256, 0, stream>>>(Y, w1k, a1w1, a1b1, a1w2, a1b2, C1, stats);
    k_statfin<<<1, 64, 0, stream>>>(stats, g1, b1, ssf, 4096.f * 432.f);
    k_conv2<<<NSAMP, 256, 0, stream>>>(C1, w2k, a2w1, a2b1, a2w2, a2b2, ssf, H2, stats + 32);
    k_statfin<<<1, 64, 0, stream>>>(stats + 32, g2, b2, ssf + 32, 4096.f * 405.f);
    k_fc<<<NSAMP, 256, 0, stream>>>(H2, ssf + 32, fcw, fcb, (float*)d_out);
}

// Round 2
// 603.551 us; speedup vs baseline: 2.3193x; 2.3193x over previous
//
#include <hip/hip_runtime.h>
#include <math.h>

// Problem constants
#define NB   216        // kept bins
#define W1   432        // transform width = conv1 width
#define W2   405        // conv2 output width
#define NSAMP 4096
#define NFFTC 1747

// ws layout (in floats):
//  region A (Y then H2T): max(32768*432, 4096*16*405) = 26,542,080 floats
//  C1: 4096*16*432 = 28,311,552 floats
//  basis (padded to 448 cols): 448*512 = 229,376 floats
//  stats raw 64 | finalized 64 | fcwT 25920
#define AREG   26542080
#define C1SZ   28311552
#define BASSZ  (448*512)

typedef __bf16 bf16x8 __attribute__((ext_vector_type(8)));
typedef float  f32x4  __attribute__((ext_vector_type(4)));

// ---------------------------------------------------------------- basis table
__global__ void k_basis(float* __restrict__ bas) {
    int idx = blockIdx.x * 256 + threadIdx.x;   // 448*512 total
    int w = idx >> 9, t = idx & 511;
    float v = 0.f;
    if (w < W1) {
        int k = (w < NB) ? (24 + w) : (w - 192);      // 24..239
        int m = (k * t) % NFFTC;                       // exact
        float ang = (float)m * (float)(6.283185307179586 / 1747.0);
        float c = (w < NB) ? cosf(ang) : -sinf(ang);   // rfft: Re=+cos, Im=-sin
        v = c * (1.f / 512.f);
    }
    bas[idx] = v;
}

// ---------------------------------------------------------------- DFT as GEMM
__global__ __launch_bounds__(256) void k_dft(const float* __restrict__ xg,
                                             const float* __restrict__ bas,
                                             float* __restrict__ Y) {
    __shared__ float As[32][129];
    __shared__ float Bs[32][65];
    int nt = blockIdx.x;              // 0..6
    int mt = blockIdx.y;              // 0..255
    int tid = threadIdx.x;
    int rowbase = mt * 128, colbase = nt * 64;
    int tx = tid & 15, ty = tid >> 4;
    float acc[8][4] = {};
    for (int k0 = 0; k0 < 512; k0 += 32) {
        #pragma unroll
        for (int i = 0; i < 16; ++i) {
            int idx = i * 256 + tid;
            int m = idx >> 5, kk = idx & 31;
            As[kk][m] = xg[(rowbase + m) * 512 + k0 + kk];
        }
        #pragma unroll
        for (int i = 0; i < 8; ++i) {
            int idx = i * 256 + tid;
            int w = idx >> 5, kk = idx & 31;
            Bs[kk][w] = bas[(colbase + w) * 512 + k0 + kk];
        }
        __syncthreads();
        #pragma unroll
        for (int kk = 0; kk < 32; ++kk) {
            float a[8], b[4];
            #pragma unroll
            for (int i = 0; i < 8; ++i) a[i] = As[kk][ty * 8 + i];
            #pragma unroll
            for (int j = 0; j < 4; ++j) b[j] = Bs[kk][tx * 4 + j];
            #pragma unroll
            for (int i = 0; i < 8; ++i)
                #pragma unroll
                for (int j = 0; j < 4; ++j)
                    acc[i][j] = fmaf(a[i], b[j], acc[i][j]);
        }
        __syncthreads();
    }
    #pragma unroll
    for (int i = 0; i < 8; ++i) {
        int r = rowbase + ty * 8 + i;
        #pragma unroll
        for (int j = 0; j < 4; ++j) {
            int w = colbase + tx * 4 + j;
            if (w < W1) Y[r * W1 + w] = acc[i][j];
        }
    }
}

// ------------------------------------------------- conv1 (+att1, + BN1 stats)
__global__ __launch_bounds__(256) void k_conv1(const float* __restrict__ Y,
        const float* __restrict__ w1k, const float* __restrict__ a1w1,
        const float* __restrict__ a1b1, const float* __restrict__ a1w2,
        const float* __restrict__ a1b2,
        float* __restrict__ C1, float* __restrict__ stats) {
    __shared__ float Ys[8 * W1];
    __shared__ float kers[128];
    __shared__ float red[4];
    int b = blockIdx.x, tid = threadIdx.x;
    const float* yb = Y + b * (8 * W1);
    float psum = 0.f;
    for (int idx = tid; idx < 8 * W1; idx += 256) {
        float v = yb[idx]; Ys[idx] = v; psum += v;
    }
    #pragma unroll
    for (int m = 32; m; m >>= 1) psum += __shfl_xor(psum, m);
    if ((tid & 63) == 0) red[tid >> 6] = psum;
    __syncthreads();
    float p1 = (red[0] + red[1] + red[2] + red[3]) * (1.f / (8.f * W1));
    float h = fmaxf(p1 * a1w1[0] + a1b1[0], 0.f);
    float l[4], mx = -1e30f;
    #pragma unroll
    for (int k = 0; k < 4; ++k) { l[k] = (h * a1w2[k] + a1b2[k]) * (1.f / 30.f); mx = fmaxf(mx, l[k]); }
    float es = 0.f;
    #pragma unroll
    for (int k = 0; k < 4; ++k) { l[k] = expf(l[k] - mx); es += l[k]; }
    float inv = 1.f / es;
    if (tid < 128) {
        float kv = 0.f;
        #pragma unroll
        for (int k = 0; k < 4; ++k) kv += l[k] * inv * w1k[k * 128 + tid];
        kers[tid] = kv;
    }
    __syncthreads();
    int o = tid >> 4, wl = tid & 15;
    float kr[8];
    #pragma unroll
    for (int hh = 0; hh < 8; ++hh) kr[hh] = kers[o * 8 + hh];
    float ssum = 0.f, ssq = 0.f;
    float* c1b = C1 + (b * 16 + o) * W1;
    #pragma unroll 3
    for (int j = 0; j < 27; ++j) {
        int w = wl + 16 * j;
        float acc = 0.f;
        #pragma unroll
        for (int hh = 0; hh < 8; ++hh) acc = fmaf(kr[hh], Ys[hh * W1 + w], acc);
        c1b[w] = acc;
        ssum += acc; ssq = fmaf(acc, acc, ssq);
    }
    #pragma unroll
    for (int m = 1; m < 16; m <<= 1) { ssum += __shfl_xor(ssum, m); ssq += __shfl_xor(ssq, m); }
    if (wl == 0) { atomicAdd(&stats[o], ssum); atomicAdd(&stats[16 + o], ssq); }
}

// ------------------------------------------------------------- stats finalize
__global__ void k_statfin(const float* __restrict__ stats, const float* __restrict__ g,
                          const float* __restrict__ bb, float* __restrict__ ss, float cnt) {
    int i = threadIdx.x;
    if (i < 16) {
        float mean = stats[i] / cnt;
        float var  = stats[16 + i] / cnt - mean * mean;
        float istd = rsqrtf(var + 1e-5f);
        float sc = g[i] * istd;
        ss[i] = sc;
        ss[16 + i] = bb[i] - mean * sc;
    }
}

// -------------------------------- conv2 via MFMA (BN1+relu fused, att2, stats)
// GEMM per sample: H2T[w][oc] = sum_k A[w][k] * B[k][oc], k = tp*16+ic (K=160)
// A[w][k] = H1[ic][w+3*tp]  (read from transposed LDS H1T[w'][ic])
// B[k][oc] = attention-mixed kernel, im2col'd into Bl[oc][tp*16+ic]
#define H1T_STR 24     // shorts per row (pad 16->24 to de-phase banks)
#define H1T_ROWS 448
__global__ __launch_bounds__(256) void k_conv2(const float* __restrict__ C1,
        const float* __restrict__ w2k, const float* __restrict__ a2w1,
        const float* __restrict__ a2b1, const float* __restrict__ a2w2,
        const float* __restrict__ a2b2, const float* __restrict__ ss,
        float* __restrict__ H2T, float* __restrict__ stats2) {
    __shared__ __attribute__((aligned(16))) unsigned short H1T[H1T_ROWS * H1T_STR];
    __shared__ __attribute__((aligned(16))) unsigned short Bl[16 * 160];
    __shared__ float p2w[4][16];
    __shared__ float sred[4][2][16];
    int b = blockIdx.x, tid = threadIdx.x;
    int wv = tid >> 6, lane = tid & 63;

    // ---- stage C1 -> BN1+relu -> bf16 -> H1T (transposed), accumulate means
    int icp = tid & 7;            // ic pair index
    int wsl = tid >> 3;           // 0..31
    int ic0 = icp * 2, ic1 = ic0 + 1;
    float sc0 = ss[ic0], sh0 = ss[16 + ic0], sc1 = ss[ic1], sh1 = ss[16 + ic1];
    const float* cb0 = C1 + (b * 16 + ic0) * W1;
    const float* cb1 = C1 + (b * 16 + ic1) * W1;
    float ps0 = 0.f, ps1 = 0.f;
    for (int w = wsl; w < W1; w += 32) {
        float v0 = fmaxf(fmaf(cb0[w], sc0, sh0), 0.f);
        float v1 = fmaxf(fmaf(cb1[w], sc1, sh1), 0.f);
        ps0 += v0; ps1 += v1;
        unsigned int u0 = __builtin_bit_cast(unsigned short, (__bf16)v0);
        unsigned int u1 = __builtin_bit_cast(unsigned short, (__bf16)v1);
        *(unsigned int*)&H1T[w * H1T_STR + ic0] = u0 | (u1 << 16);
    }
    if (tid < 128) {   // zero pad rows 432..447 (ic cols 0..15)
        int r = 432 + (tid >> 3), c = (tid & 7) * 2;
        *(unsigned int*)&H1T[r * H1T_STR + c] = 0u;
    }
    // reduce ps over the 8 lanes in this wave sharing icp (lane bits 3..5)
    ps0 += __shfl_xor(ps0, 8);  ps1 += __shfl_xor(ps1, 8);
    ps0 += __shfl_xor(ps0, 16); ps1 += __shfl_xor(ps1, 16);
    ps0 += __shfl_xor(ps0, 32); ps1 += __shfl_xor(ps1, 32);
    if (lane < 8) { p2w[wv][lane * 2] = ps0; p2w[wv][lane * 2 + 1] = ps1; }
    __syncthreads();

    // ---- att2 (redundant per-thread, cheap; uniform -> scalar loads)
    float hv[4];
    #pragma unroll
    for (int j = 0; j < 4; ++j) {
        float a = a2b1[j];
        #pragma unroll
        for (int i = 0; i < 16; ++i) {
            float p2 = (p2w[0][i] + p2w[1][i] + p2w[2][i] + p2w[3][i]) * (1.f / (float)W1);
            a = fmaf(a2w1[j * 16 + i], p2, a);
        }
        hv[j] = fmaxf(a, 0.f);
    }
    float l[4], mx = -1e30f;
    #pragma unroll
    for (int k = 0; k < 4; ++k) {
        float a = a2b2[k];
        #pragma unroll
        for (int j = 0; j < 4; ++j) a = fmaf(a2w2[k * 4 + j], hv[j], a);
        l[k] = a * (1.f / 30.f); mx = fmaxf(mx, l[k]);
    }
    float es = 0.f;
    #pragma unroll
    for (int k = 0; k < 4; ++k) { l[k] = expf(l[k] - mx); es += l[k]; }
    float inv = 1.f / es;
    float at0 = l[0] * inv, at1 = l[1] * inv, at2 = l[2] * inv, at3 = l[3] * inv;
    // ---- mixed kernel, im2col'd: Bl[oc][tp*16+ic] (src w2k[k][oc][ic][0][tp])
    for (int idx = tid; idx < 2560; idx += 256) {
        int oc = idx / 160, rem = idx - oc * 160;
        int tp = rem >> 4, ic = rem & 15;
        int so = oc * 160 + ic * 10 + tp;
        float v = at0 * w2k[so] + at1 * w2k[2560 + so] + at2 * w2k[5120 + so] + at3 * w2k[7680 + so];
        Bl[idx] = __builtin_bit_cast(unsigned short, (__bf16)v);
    }
    __syncthreads();

    // ---- MFMA main loop: 26 m-tiles of 16 w's, K=160 in 5 steps of 32
    int col = lane & 15, kg = lane >> 4;          // col: A-row (w) & B-col (oc)
    bf16x8 bfrag[5];
    #pragma unroll
    for (int s = 0; s < 5; ++s)
        bfrag[s] = *(const bf16x8*)&Bl[col * 160 + s * 32 + kg * 8];
    float s2 = 0.f, q2 = 0.f;
    for (int mt = wv; mt < 26; mt += 4) {
        int wbase = mt * 16;
        f32x4 acc = {0.f, 0.f, 0.f, 0.f};
        #pragma unroll
        for (int s = 0; s < 5; ++s) {
            int tp = 2 * s + (kg >> 1);
            int row = wbase + col + 3 * tp;
            bf16x8 a = *(const bf16x8*)&H1T[row * H1T_STR + (kg & 1) * 8];
            acc = __builtin_amdgcn_mfma_f32_16x16x32_bf16(a, bfrag[s], acc, 0, 0, 0);
        }
        // D: lane holds D[w=wbase+(lane>>4)*4+r][oc=lane&15]
        float* hb = H2T + (size_t)b * (16 * W2) + (wbase + kg * 4) * 16 + col;
        #pragma unroll
        for (int r = 0; r < 4; ++r) {
            int w = wbase + kg * 4 + r;
            if (w < W2) {
                float v = acc[r];
                hb[r * 16] = v;
                s2 += v; q2 = fmaf(v, v, q2);
            }
        }
    }
    // stats: combine lane-groups sharing oc=lane&15, then across waves via LDS
    s2 += __shfl_xor(s2, 16); q2 += __shfl_xor(q2, 16);
    s2 += __shfl_xor(s2, 32); q2 += __shfl_xor(q2, 32);
    if (lane < 16) { sred[wv][0][lane] = s2; sred[wv][1][lane] = q2; }
    __syncthreads();
    if (tid < 16) {
        atomicAdd(&stats2[tid],      sred[0][0][tid] + sred[1][0][tid] + sred[2][0][tid] + sred[3][0][tid]);
        atomicAdd(&stats2[16 + tid], sred[0][1][tid] + sred[1][1][tid] + sred[2][1][tid] + sred[3][1][tid]);
    }
}

// ----------------------------------------------------- fcw transpose (once)
// fcwT[(w*16+oc)*4 + n] = fcw[n*6480 + oc*405 + w]
__global__ void k_fcT(const float* __restrict__ fcw, float* __restrict__ fcwT) {
    int idx = blockIdx.x * 256 + threadIdx.x;
    if (idx < 4 * 16 * W2) {
        int n = idx & 3, p = idx >> 2;
        int w = p >> 4, oc = p & 15;
        fcwT[idx] = fcw[n * (16 * W2) + oc * W2 + w];
    }
}

// ------------------------------------------------------------ BN2+relu+FC out
__global__ __launch_bounds__(256) void k_fc(const float* __restrict__ H2T,
        const float* __restrict__ ss2, const float* __restrict__ fcwT,
        const float* __restrict__ fcb, float* __restrict__ out) {
    __shared__ float red[4][4];
    int b = blockIdx.x, tid = threadIdx.x;
    const float* hb = H2T + (size_t)b * (16 * W2);
    const f32x4* ft = (const f32x4*)fcwT;
    float acc[4] = {};
    for (int idx = tid; idx < 16 * W2; idx += 256) {
        int oc = idx & 15;
        float v = fmaxf(fmaf(hb[idx], ss2[oc], ss2[16 + oc]), 0.f);
        f32x4 wv4 = ft[idx];
        #pragma unroll
        for (int n = 0; n < 4; ++n) acc[n] = fmaf(v, wv4[n], acc[n]);
    }
    #pragma unroll
    for (int m = 1; m < 64; m <<= 1)
        #pragma unroll
        for (int n = 0; n < 4; ++n) acc[n] += __shfl_xor(acc[n], m);
    int wid = tid >> 6, lane = tid & 63;
    if (lane == 0) {
        #pragma unroll
        for (int n = 0; n < 4; ++n) red[wid][n] = acc[n];
    }
    __syncthreads();
    if (tid < 4)
        out[b * 4 + tid] = red[0][tid] + red[1][tid] + red[2][tid] + red[3][tid] + fcb[tid];
}

extern "C" void kernel_launch(void* const* d_in, const int* in_sizes, int n_in,
                              void* d_out, int out_size, void* d_ws, size_t ws_size,
                              hipStream_t stream) {
    const float* x    = (const float*)d_in[0];
    const float* w1k  = (const float*)d_in[1];
    const float* a1w1 = (const float*)d_in[2];
    const float* a1b1 = (const float*)d_in[3];
    const float* a1w2 = (const float*)d_in[4];
    const float* a1b2 = (const float*)d_in[5];
    const float* g1   = (const float*)d_in[6];
    const float* b1   = (const float*)d_in[7];
    const float* w2k  = (const float*)d_in[8];
    const float* a2w1 = (const float*)d_in[9];
    const float* a2b1 = (const float*)d_in[10];
    const float* a2w2 = (const float*)d_in[11];
    const float* a2b2 = (const float*)d_in[12];
    const float* g2   = (const float*)d_in[13];
    const float* b2   = (const float*)d_in[14];
    const float* fcw  = (const float*)d_in[15];
    const float* fcb  = (const float*)d_in[16];

    float* ws    = (float*)d_ws;
    float* Y     = ws;                 // region A (dead after conv1)
    float* H2T   = ws;                 // region A reused, [b][w][oc]
    float* C1    = ws + AREG;
    float* bas   = ws + AREG + C1SZ;
    float* stats = bas + BASSZ;        // raw: [s1sum16][s1sq16][s2sum16][s2sq16]
    float* ssf   = stats + 64;         // finalized: [sc1 16][sh1 16][sc2 16][sh2 16]
    float* fcwT  = ssf + 64;           // 25920 floats

    hipMemsetAsync(stats, 0, 64 * sizeof(float), stream);
    k_fcT<<<(4 * 16 * W2 + 255) / 256, 256, 0, stream>>>(fcw, fcwT);
    k_basis<<<BASSZ / 256, 256, 0, stream>>>(bas);
    k_dft<<<dim3(7, 256), 256, 0, stream>>>(x, bas, Y);
    k_conv1<<<NSAMP, 256, 0, stream>>>(Y, w1k, a1w1, a1b1, a1w2, a1b2, C1, stats);
    k_statfin<<<1, 64, 0, stream>>>(stats, g1, b1, ssf, 4096.f * 432.f);
    k_conv2<<<NSAMP, 256, 0, stream>>>(C1, w2k, a2w1, a2b1, a2w2, a2b2, ssf, H2T, stats + 32);
    k_statfin<<<1, 64, 0, stream>>>(stats + 32, g2, b2, ssf + 32, 4096.f * 405.f);
    k_fc<<<NSAMP, 256, 0, stream>>>(H2T, ssf + 32, fcwT, fcb, (float*)d_out);
}

// Round 3
// 400.081 us; speedup vs baseline: 3.4989x; 1.5086x over previous
//
#include <hip/hip_runtime.h>
#include <math.h>

// Problem constants
#define NB   216        // kept bins
#define W1   432        // transform width = conv1 width
#define W2   405        // conv2 output width
#define NSAMP 4096
#define NFFTC 1747

typedef __bf16 bf16x8 __attribute__((ext_vector_type(8)));
typedef float  f32x4  __attribute__((ext_vector_type(4)));
typedef unsigned int u32x4 __attribute__((ext_vector_type(4)));

__device__ __forceinline__ unsigned int bfbits(float f) {
    return (unsigned int)__builtin_bit_cast(unsigned short, (__bf16)f);
}
__device__ __forceinline__ void gload_lds16(const void* g, void* l) {
    __builtin_amdgcn_global_load_lds(
        (const __attribute__((address_space(1))) unsigned int*)g,
        (__attribute__((address_space(3))) unsigned int*)l, 16, 0, 0);
}

// ------------------------------------------------------- X fp32 -> bf16 packed
// Xb layout (shorts): ((rt*8+kt)*8192) + wv*2048 + mt*1024 + ks*512 + lane*8 + e
// source: row = rt*128+wv*32+mt*16+(lane&15), k = kt*64+ks*32+(lane>>4)*8+e
__global__ __launch_bounds__(256) void k_cvt(const float* __restrict__ x,
                                             unsigned short* __restrict__ Xb) {
    int g = blockIdx.x * 256 + threadIdx.x;      // 2,097,152 groups of 8
    int lane = g & 63;
    int t1 = g >> 6;  int ks = t1 & 1;
    int t2 = t1 >> 1; int mt = t2 & 1;
    int t3 = t2 >> 1; int wv = t3 & 3;
    int t4 = t3 >> 2; int kt = t4 & 7;
    int rt = t4 >> 3;
    int row = rt * 128 + wv * 32 + mt * 16 + (lane & 15);
    int k   = kt * 64 + ks * 32 + (lane >> 4) * 8;
    const float* src = x + (size_t)row * 512 + k;
    f32x4 a = *(const f32x4*)src;
    f32x4 b = *(const f32x4*)(src + 4);
    u32x4 v;
    v[0] = bfbits(a[0]) | (bfbits(a[1]) << 16);
    v[1] = bfbits(a[2]) | (bfbits(a[3]) << 16);
    v[2] = bfbits(b[0]) | (bfbits(b[1]) << 16);
    v[3] = bfbits(b[2]) | (bfbits(b[3]) << 16);
    *(u32x4*)(Xb + (size_t)g * 8) = v;
}

// --------------------------------------------- basis table, bf16 packed layout
// basf (shorts): ct*32768 + kt*4096 + nt*1024 + ks*512 + lane*8 + e
// w = ct*64+nt*16+(lane&15), t = kt*64+ks*32+(lane>>4)*8+e
__global__ __launch_bounds__(256) void k_basis(unsigned short* __restrict__ basf) {
    int g = blockIdx.x * 256 + threadIdx.x;      // 28,672 groups of 8
    int lane = g & 63;
    int t1 = g >> 6;  int ks = t1 & 1;
    int t2 = t1 >> 1; int nt = t2 & 3;
    int t3 = t2 >> 2; int kt = t3 & 7;
    int ct = t3 >> 3;
    int w  = ct * 64 + nt * 16 + (lane & 15);
    int t0 = kt * 64 + ks * 32 + (lane >> 4) * 8;
    unsigned int p[4] = {0u, 0u, 0u, 0u};
    if (w < W1) {
        int k = (w < NB) ? (24 + w) : (w - 192);
        #pragma unroll
        for (int e = 0; e < 8; ++e) {
            int m = (k * (t0 + e)) % NFFTC;
            float ang = (float)m * (float)(6.283185307179586 / 1747.0);
            float c = (w < NB) ? cosf(ang) : -sinf(ang);
            unsigned int bits = bfbits(c * (1.f / 512.f));
            p[e >> 1] |= bits << ((e & 1) * 16);
        }
    }
    u32x4 v = {p[0], p[1], p[2], p[3]};
    *(u32x4*)(basf + (size_t)g * 8) = v;
}

// ------------------------------------------------------------ DFT via MFMA
// Y[32768,432] = X[32768,512] @ B[512,448(432)] ; 128x64 tile, BK=64, 4 waves
__global__ __launch_bounds__(256) void k_dft(const unsigned short* __restrict__ Xb,
        const unsigned short* __restrict__ basf, float* __restrict__ Y) {
    __shared__ __attribute__((aligned(16))) unsigned short Al[8192];  // 16 KB
    __shared__ __attribute__((aligned(16))) unsigned short Bl[4096];  //  8 KB
    int ct = blockIdx.x, rt = blockIdx.y;
    int tid = threadIdx.x, wv = tid >> 6, lane = tid & 63;
    const char* asrc = (const char*)(Xb + (size_t)rt * 65536);
    const char* bsrc = (const char*)(basf + (size_t)ct * 32768);
    f32x4 acc[2][4];
    #pragma unroll
    for (int mt = 0; mt < 2; ++mt)
        #pragma unroll
        for (int nt = 0; nt < 4; ++nt) acc[mt][nt] = (f32x4){0.f, 0.f, 0.f, 0.f};

    for (int kt = 0; kt < 8; ++kt) {
        if (kt) __syncthreads();
        #pragma unroll
        for (int i = 0; i < 4; ++i)
            gload_lds16(asrc + kt * 16384 + wv * 4096 + i * 1024 + lane * 16,
                        &Al[wv * 2048 + i * 512]);
        #pragma unroll
        for (int i = 0; i < 2; ++i)
            gload_lds16(bsrc + kt * 8192 + wv * 2048 + i * 1024 + lane * 16,
                        &Bl[wv * 1024 + i * 512]);
        __syncthreads();   // drains vmcnt(0): gload_lds complete

        bf16x8 fa[2][2], fb[4][2];
        #pragma unroll
        for (int mt = 0; mt < 2; ++mt)
            #pragma unroll
            for (int ks = 0; ks < 2; ++ks)
                fa[mt][ks] = *(const bf16x8*)&Al[wv * 2048 + mt * 1024 + ks * 512 + lane * 8];
        #pragma unroll
        for (int nt = 0; nt < 4; ++nt)
            #pragma unroll
            for (int ks = 0; ks < 2; ++ks)
                fb[nt][ks] = *(const bf16x8*)&Bl[nt * 1024 + ks * 512 + lane * 8];
        #pragma unroll
        for (int ks = 0; ks < 2; ++ks)
            #pragma unroll
            for (int mt = 0; mt < 2; ++mt)
                #pragma unroll
                for (int nt = 0; nt < 4; ++nt)
                    acc[mt][nt] = __builtin_amdgcn_mfma_f32_16x16x32_bf16(
                        fa[mt][ks], fb[nt][ks], acc[mt][nt], 0, 0, 0);
    }
    // D: col = lane&15 (w-col), row = (lane>>4)*4 + r (x-row)
    int kg = lane >> 4, col = lane & 15;
    #pragma unroll
    for (int mt = 0; mt < 2; ++mt) {
        int rbase = rt * 128 + wv * 32 + mt * 16 + kg * 4;
        #pragma unroll
        for (int nt = 0; nt < 4; ++nt) {
            int w = ct * 64 + nt * 16 + col;
            if (w < W1) {
                #pragma unroll
                for (int r = 0; r < 4; ++r)
                    Y[(rbase + r) * W1 + w] = acc[mt][nt][r];
            }
        }
    }
}

// ------------------------------------------------- conv1 (+att1, + BN1 stats)
__global__ __launch_bounds__(256) void k_conv1(const float* __restrict__ Y,
        const float* __restrict__ w1k, const float* __restrict__ a1w1,
        const float* __restrict__ a1b1, const float* __restrict__ a1w2,
        const float* __restrict__ a1b2,
        unsigned short* __restrict__ C1b, float* __restrict__ stats) {
    __shared__ float Ys[8 * W1];
    __shared__ float kers[128];
    __shared__ float red[4];
    int b = blockIdx.x, tid = threadIdx.x;
    const float* yb = Y + (size_t)b * (8 * W1);
    float psum = 0.f;
    for (int idx = tid; idx < 8 * W1; idx += 256) {
        float v = yb[idx]; Ys[idx] = v; psum += v;
    }
    #pragma unroll
    for (int m = 32; m; m >>= 1) psum += __shfl_xor(psum, m);
    if ((tid & 63) == 0) red[tid >> 6] = psum;
    __syncthreads();
    float p1 = (red[0] + red[1] + red[2] + red[3]) * (1.f / (8.f * W1));
    float h = fmaxf(p1 * a1w1[0] + a1b1[0], 0.f);
    float l[4], mx = -1e30f;
    #pragma unroll
    for (int k = 0; k < 4; ++k) { l[k] = (h * a1w2[k] + a1b2[k]) * (1.f / 30.f); mx = fmaxf(mx, l[k]); }
    float es = 0.f;
    #pragma unroll
    for (int k = 0; k < 4; ++k) { l[k] = expf(l[k] - mx); es += l[k]; }
    float inv = 1.f / es;
    if (tid < 128) {
        float kv = 0.f;
        #pragma unroll
        for (int k = 0; k < 4; ++k) kv += l[k] * inv * w1k[k * 128 + tid];
        kers[tid] = kv;
    }
    __syncthreads();
    int o = tid >> 4, wl = tid & 15;
    float kr[8];
    #pragma unroll
    for (int hh = 0; hh < 8; ++hh) kr[hh] = kers[o * 8 + hh];
    float ssum = 0.f, ssq = 0.f;
    unsigned short* c1b = C1b + ((size_t)b * 16 + o) * W1;
    #pragma unroll 3
    for (int j = 0; j < 27; ++j) {
        int w = wl + 16 * j;
        float acc = 0.f;
        #pragma unroll
        for (int hh = 0; hh < 8; ++hh) acc = fmaf(kr[hh], Ys[hh * W1 + w], acc);
        c1b[w] = (unsigned short)bfbits(acc);
        ssum += acc; ssq = fmaf(acc, acc, ssq);
    }
    #pragma unroll
    for (int m = 1; m < 16; m <<= 1) { ssum += __shfl_xor(ssum, m); ssq += __shfl_xor(ssq, m); }
    if (wl == 0) { atomicAdd(&stats[o], ssum); atomicAdd(&stats[16 + o], ssq); }
}

// ------------------------------------------------------------- stats finalize
__global__ void k_statfin(const float* __restrict__ stats, const float* __restrict__ g,
                          const float* __restrict__ bb, float* __restrict__ ss, float cnt) {
    int i = threadIdx.x;
    if (i < 16) {
        float mean = stats[i] / cnt;
        float var  = stats[16 + i] / cnt - mean * mean;
        float istd = rsqrtf(var + 1e-5f);
        float sc = g[i] * istd;
        ss[i] = sc;
        ss[16 + i] = bb[i] - mean * sc;
    }
}

// -------------------------------- conv2 via MFMA (BN1+relu fused, att2, stats)
#define H1T_STR 24     // shorts per row
#define H1T_ROWS 448
__global__ __launch_bounds__(256) void k_conv2(const unsigned short* __restrict__ C1b,
        const float* __restrict__ w2k, const float* __restrict__ a2w1,
        const float* __restrict__ a2b1, const float* __restrict__ a2w2,
        const float* __restrict__ a2b2, const float* __restrict__ ss,
        float* __restrict__ H2T, float* __restrict__ stats2) {
    __shared__ __attribute__((aligned(16))) unsigned short H1T[H1T_ROWS * H1T_STR];
    __shared__ __attribute__((aligned(16))) unsigned short Bl[16 * 160];
    __shared__ float p2s[16];
    __shared__ float sred[4][2][16];
    int b = blockIdx.x, tid = threadIdx.x;
    int wv = tid >> 6, lane = tid & 63;

    // ---- stage C1(bf16) -> BN1+relu -> bf16 -> H1T (transposed), means
    int wsl = tid & 31;           // consecutive w -> coalesced 64B reads
    int icp = tid >> 5;           // 0..7 channel pair
    int ic0 = icp * 2, ic1 = ic0 + 1;
    float sc0 = ss[ic0], sh0 = ss[16 + ic0], sc1 = ss[ic1], sh1 = ss[16 + ic1];
    const __bf16* cb0 = (const __bf16*)(C1b + ((size_t)b * 16 + ic0) * W1);
    const __bf16* cb1 = (const __bf16*)(C1b + ((size_t)b * 16 + ic1) * W1);
    float ps0 = 0.f, ps1 = 0.f;
    for (int w = wsl; w < W1; w += 32) {
        float v0 = fmaxf(fmaf((float)cb0[w], sc0, sh0), 0.f);
        float v1 = fmaxf(fmaf((float)cb1[w], sc1, sh1), 0.f);
        ps0 += v0; ps1 += v1;
        *(unsigned int*)&H1T[w * H1T_STR + ic0] = bfbits(v0) | (bfbits(v1) << 16);
    }
    if (tid < 128) {   // zero pad rows 432..447
        int r = 432 + (tid >> 3), c = (tid & 7) * 2;
        *(unsigned int*)&H1T[r * H1T_STR + c] = 0u;
    }
    #pragma unroll
    for (int m = 1; m < 32; m <<= 1) { ps0 += __shfl_xor(ps0, m); ps1 += __shfl_xor(ps1, m); }
    if ((lane & 31) == 0) { p2s[ic0] = ps0 * (1.f / (float)W1); p2s[ic1] = ps1 * (1.f / (float)W1); }
    __syncthreads();

    // ---- att2 (redundant per-thread, cheap)
    float hv[4];
    #pragma unroll
    for (int j = 0; j < 4; ++j) {
        float a = a2b1[j];
        #pragma unroll
        for (int i = 0; i < 16; ++i) a = fmaf(a2w1[j * 16 + i], p2s[i], a);
        hv[j] = fmaxf(a, 0.f);
    }
    float l[4], mx = -1e30f;
    #pragma unroll
    for (int k = 0; k < 4; ++k) {
        float a = a2b2[k];
        #pragma unroll
        for (int j = 0; j < 4; ++j) a = fmaf(a2w2[k * 4 + j], hv[j], a);
        l[k] = a * (1.f / 30.f); mx = fmaxf(mx, l[k]);
    }
    float es = 0.f;
    #pragma unroll
    for (int k = 0; k < 4; ++k) { l[k] = expf(l[k] - mx); es += l[k]; }
    float inv = 1.f / es;
    float at0 = l[0] * inv, at1 = l[1] * inv, at2 = l[2] * inv, at3 = l[3] * inv;
    // ---- mixed kernel im2col: Bl[oc][tp*16+ic]
    for (int idx = tid; idx < 2560; idx += 256) {
        int oc = idx / 160, rem = idx - oc * 160;
        int tp = rem >> 4, ic = rem & 15;
        int so = oc * 160 + ic * 10 + tp;
        float v = at0 * w2k[so] + at1 * w2k[2560 + so] + at2 * w2k[5120 + so] + at3 * w2k[7680 + so];
        Bl[idx] = (unsigned short)bfbits(v);
    }
    __syncthreads();

    // ---- MFMA: 26 m-tiles of 16 w's, K=160 in 5 steps of 32
    int col = lane & 15, kg = lane >> 4;
    bf16x8 bfrag[5];
    #pragma unroll
    for (int s = 0; s < 5; ++s)
        bfrag[s] = *(const bf16x8*)&Bl[col * 160 + s * 32 + kg * 8];
    float s2 = 0.f, q2 = 0.f;
    for (int mt = wv; mt < 26; mt += 4) {
        int wbase = mt * 16;
        f32x4 acc = {0.f, 0.f, 0.f, 0.f};
        #pragma unroll
        for (int s = 0; s < 5; ++s) {
            int tp = 2 * s + (kg >> 1);
            int row = wbase + col + 3 * tp;
            bf16x8 a = *(const bf16x8*)&H1T[row * H1T_STR + (kg & 1) * 8];
            acc = __builtin_amdgcn_mfma_f32_16x16x32_bf16(a, bfrag[s], acc, 0, 0, 0);
        }
        float* hb = H2T + (size_t)b * (16 * W2) + (wbase + kg * 4) * 16 + col;
        #pragma unroll
        for (int r = 0; r < 4; ++r) {
            int w = wbase + kg * 4 + r;
            if (w < W2) {
                float v = acc[r];
                hb[r * 16] = v;
                s2 += v; q2 = fmaf(v, v, q2);
            }
        }
    }
    s2 += __shfl_xor(s2, 16); q2 += __shfl_xor(q2, 16);
    s2 += __shfl_xor(s2, 32); q2 += __shfl_xor(q2, 32);
    if (lane < 16) { sred[wv][0][lane] = s2; sred[wv][1][lane] = q2; }
    __syncthreads();
    if (tid < 16) {
        atomicAdd(&stats2[tid],      sred[0][0][tid] + sred[1][0][tid] + sred[2][0][tid] + sred[3][0][tid]);
        atomicAdd(&stats2[16 + tid], sred[0][1][tid] + sred[1][1][tid] + sred[2][1][tid] + sred[3][1][tid]);
    }
}

// ----------------------------------------------------- fcw transpose (once)
__global__ void k_fcT(const float* __restrict__ fcw, float* __restrict__ fcwT) {
    int idx = blockIdx.x * 256 + threadIdx.x;
    if (idx < 4 * 16 * W2) {
        int n = idx & 3, p = idx >> 2;
        int w = p >> 4, oc = p & 15;
        fcwT[idx] = fcw[n * (16 * W2) + oc * W2 + w];
    }
}

// ------------------------------------------------------------ BN2+relu+FC out
__global__ __launch_bounds__(256) void k_fc(const float* __restrict__ H2T,
        const float* __restrict__ ss2, const float* __restrict__ fcwT,
        const float* __restrict__ fcb, float* __restrict__ out) {
    __shared__ float red[4][4];
    int b = blockIdx.x, tid = threadIdx.x;
    const float* hb = H2T + (size_t)b * (16 * W2);
    const f32x4* ft = (const f32x4*)fcwT;
    float acc[4] = {};
    for (int idx = tid; idx < 16 * W2; idx += 256) {
        int oc = idx & 15;
        float v = fmaxf(fmaf(hb[idx], ss2[oc], ss2[16 + oc]), 0.f);
        f32x4 wv4 = ft[idx];
        #pragma unroll
        for (int n = 0; n < 4; ++n) acc[n] = fmaf(v, wv4[n], acc[n]);
    }
    #pragma unroll
    for (int m = 1; m < 64; m <<= 1)
        #pragma unroll
        for (int n = 0; n < 4; ++n) acc[n] += __shfl_xor(acc[n], m);
    int wid = tid >> 6, lane = tid & 63;
    if (lane == 0) {
        #pragma unroll
        for (int n = 0; n < 4; ++n) red[wid][n] = acc[n];
    }
    __syncthreads();
    if (tid < 4)
        out[b * 4 + tid] = red[0][tid] + red[1][tid] + red[2][tid] + red[3][tid] + fcb[tid];
}

extern "C" void kernel_launch(void* const* d_in, const int* in_sizes, int n_in,
                              void* d_out, int out_size, void* d_ws, size_t ws_size,
                              hipStream_t stream) {
    const float* x    = (const float*)d_in[0];
    const float* w1k  = (const float*)d_in[1];
    const float* a1w1 = (const float*)d_in[2];
    const float* a1b1 = (const float*)d_in[3];
    const float* a1w2 = (const float*)d_in[4];
    const float* a1b2 = (const float*)d_in[5];
    const float* g1   = (const float*)d_in[6];
    const float* b1   = (const float*)d_in[7];
    const float* w2k  = (const float*)d_in[8];
    const float* a2w1 = (const float*)d_in[9];
    const float* a2b1 = (const float*)d_in[10];
    const float* a2w2 = (const float*)d_in[11];
    const float* a2b2 = (const float*)d_in[12];
    const float* g2   = (const float*)d_in[13];
    const float* b2   = (const float*)d_in[14];
    const float* fcw  = (const float*)d_in[15];
    const float* fcb  = (const float*)d_in[16];

    float* ws = (float*)d_ws;
    // Region Q: Y (dft->conv1) then H2T (conv2->fc): 26,542,080 floats
    // Region P: Xb bf16 (cvt->dft) then C1b bf16 (conv1->conv2): 14,155,776 floats
    float*          Y    = ws;
    float*          H2T  = ws;
    unsigned short* Xb   = (unsigned short*)(ws + 26542080);
    unsigned short* C1b  = (unsigned short*)(ws + 26542080);
    unsigned short* basf = (unsigned short*)(ws + 26542080 + 14155776);
    float* stats = ws + 26542080 + 14155776 + 114688;
    float* ssf   = stats + 64;
    float* fcwT  = ssf + 64;

    hipMemsetAsync(stats, 0, 64 * sizeof(float), stream);
    k_fcT<<<(4 * 16 * W2 + 255) / 256, 256, 0, stream>>>(fcw, fcwT);
    k_basis<<<112, 256, 0, stream>>>(basf);
    k_cvt<<<8192, 256, 0, stream>>>(x, Xb);
    k_dft<<<dim3(7, 256), 256, 0, stream>>>(Xb, basf, Y);
    k_conv1<<<NSAMP, 256, 0, stream>>>(Y, w1k, a1w1, a1b1, a1w2, a1b2, C1b, stats);
    k_statfin<<<1, 64, 0, stream>>>(stats, g1, b1, ssf, 4096.f * 432.f);
    k_conv2<<<NSAMP, 256, 0, stream>>>(C1b, w2k, a2w1, a2b1, a2w2, a2b2, ssf, H2T, stats + 32);
    k_statfin<<<1, 64, 0, stream>>>(stats + 32, g2, b2, ssf + 32, 4096.f * 405.f);
    k_fc<<<NSAMP, 256, 0, stream>>>(H2T, ssf + 32, fcwT, fcb, (float*)d_out);
}

// Round 4
// 189.024 us; speedup vs baseline: 7.4056x; 2.1166x over previous
//
#include <hip/hip_runtime.h>
#include <math.h>

// Problem constants
#define NB   216        // kept bins
#define W1   432        // transform width = conv1 width
#define W2   405        // conv2 output width
#define NSAMP 4096
#define NFFTC 1747

typedef __bf16 bf16x8 __attribute__((ext_vector_type(8)));
typedef float  f32x4  __attribute__((ext_vector_type(4)));
typedef unsigned int u32x4 __attribute__((ext_vector_type(4)));

__device__ __forceinline__ unsigned int bfbits(float f) {
    return (unsigned int)__builtin_bit_cast(unsigned short, (__bf16)f);
}
__device__ __forceinline__ float bf2f(unsigned int u) {
    return (float)__builtin_bit_cast(__bf16, (unsigned short)(u & 0xffff));
}
__device__ __forceinline__ void gload_lds16(const void* g, void* l) {
    __builtin_amdgcn_global_load_lds(
        (const __attribute__((address_space(1))) unsigned int*)g,
        (__attribute__((address_space(3))) unsigned int*)l, 16, 0, 0);
}

// ------------------------------------------------------- X fp32 -> bf16 packed
// Xb layout (shorts): ((rt*8+kt)*8192) + wv*2048 + mt*1024 + ks*512 + lane*8 + e
__global__ __launch_bounds__(256) void k_cvt(const float* __restrict__ x,
                                             unsigned short* __restrict__ Xb) {
    int g = blockIdx.x * 256 + threadIdx.x;      // 2,097,152 groups of 8
    int lane = g & 63;
    int t1 = g >> 6;  int ks = t1 & 1;
    int t2 = t1 >> 1; int mt = t2 & 1;
    int t3 = t2 >> 1; int wv = t3 & 3;
    int t4 = t3 >> 2; int kt = t4 & 7;
    int rt = t4 >> 3;
    int row = rt * 128 + wv * 32 + mt * 16 + (lane & 15);
    int k   = kt * 64 + ks * 32 + (lane >> 4) * 8;
    const float* src = x + (size_t)row * 512 + k;
    f32x4 a = *(const f32x4*)src;
    f32x4 b = *(const f32x4*)(src + 4);
    u32x4 v;
    v[0] = bfbits(a[0]) | (bfbits(a[1]) << 16);
    v[1] = bfbits(a[2]) | (bfbits(a[3]) << 16);
    v[2] = bfbits(b[0]) | (bfbits(b[1]) << 16);
    v[3] = bfbits(b[2]) | (bfbits(b[3]) << 16);
    *(u32x4*)(Xb + (size_t)g * 8) = v;
}

// --------------------------------------------- basis table, bf16 packed layout
__global__ __launch_bounds__(256) void k_basis(unsigned short* __restrict__ basf) {
    int g = blockIdx.x * 256 + threadIdx.x;      // 28,672 groups of 8
    int lane = g & 63;
    int t1 = g >> 6;  int ks = t1 & 1;
    int t2 = t1 >> 1; int nt = t2 & 3;
    int t3 = t2 >> 2; int kt = t3 & 7;
    int ct = t3 >> 3;
    int w  = ct * 64 + nt * 16 + (lane & 15);
    int t0 = kt * 64 + ks * 32 + (lane >> 4) * 8;
    unsigned int p[4] = {0u, 0u, 0u, 0u};
    if (w < W1) {
        int k = (w < NB) ? (24 + w) : (w - 192);
        #pragma unroll
        for (int e = 0; e < 8; ++e) {
            int m = (k * (t0 + e)) % NFFTC;
            float ang = (float)m * (float)(6.283185307179586 / 1747.0);
            float c = (w < NB) ? cosf(ang) : -sinf(ang);
            unsigned int bits = bfbits(c * (1.f / 512.f));
            p[e >> 1] |= bits << ((e & 1) * 16);
        }
    }
    u32x4 v = {p[0], p[1], p[2], p[3]};
    *(u32x4*)(basf + (size_t)g * 8) = v;
}

// ------------------------------------------------------------ DFT via MFMA
__global__ __launch_bounds__(256) void k_dft(const unsigned short* __restrict__ Xb,
        const unsigned short* __restrict__ basf, float* __restrict__ Y) {
    __shared__ __attribute__((aligned(16))) unsigned short Al[8192];  // 16 KB
    __shared__ __attribute__((aligned(16))) unsigned short Bl[4096];  //  8 KB
    int ct = blockIdx.x, rt = blockIdx.y;
    int tid = threadIdx.x, wv = tid >> 6, lane = tid & 63;
    const char* asrc = (const char*)(Xb + (size_t)rt * 65536);
    const char* bsrc = (const char*)(basf + (size_t)ct * 32768);
    f32x4 acc[2][4];
    #pragma unroll
    for (int mt = 0; mt < 2; ++mt)
        #pragma unroll
        for (int nt = 0; nt < 4; ++nt) acc[mt][nt] = (f32x4){0.f, 0.f, 0.f, 0.f};

    for (int kt = 0; kt < 8; ++kt) {
        if (kt) __syncthreads();
        #pragma unroll
        for (int i = 0; i < 4; ++i)
            gload_lds16(asrc + kt * 16384 + wv * 4096 + i * 1024 + lane * 16,
                        &Al[wv * 2048 + i * 512]);
        #pragma unroll
        for (int i = 0; i < 2; ++i)
            gload_lds16(bsrc + kt * 8192 + wv * 2048 + i * 1024 + lane * 16,
                        &Bl[wv * 1024 + i * 512]);
        __syncthreads();

        bf16x8 fa[2][2], fb[4][2];
        #pragma unroll
        for (int mt = 0; mt < 2; ++mt)
            #pragma unroll
            for (int ks = 0; ks < 2; ++ks)
                fa[mt][ks] = *(const bf16x8*)&Al[wv * 2048 + mt * 1024 + ks * 512 + lane * 8];
        #pragma unroll
        for (int nt = 0; nt < 4; ++nt)
            #pragma unroll
            for (int ks = 0; ks < 2; ++ks)
                fb[nt][ks] = *(const bf16x8*)&Bl[nt * 1024 + ks * 512 + lane * 8];
        #pragma unroll
        for (int ks = 0; ks < 2; ++ks)
            #pragma unroll
            for (int mt = 0; mt < 2; ++mt)
                #pragma unroll
                for (int nt = 0; nt < 4; ++nt)
                    acc[mt][nt] = __builtin_amdgcn_mfma_f32_16x16x32_bf16(
                        fa[mt][ks], fb[nt][ks], acc[mt][nt], 0, 0, 0);
    }
    int kg = lane >> 4, col = lane & 15;
    #pragma unroll
    for (int mt = 0; mt < 2; ++mt) {
        int rbase = rt * 128 + wv * 32 + mt * 16 + kg * 4;
        #pragma unroll
        for (int nt = 0; nt < 4; ++nt) {
            int w = ct * 64 + nt * 16 + col;
            if (w < W1) {
                #pragma unroll
                for (int r = 0; r < 4; ++r)
                    Y[(size_t)(rbase + r) * W1 + w] = acc[mt][nt][r];
            }
        }
    }
}

// ---------------------- conv1 (+att1); BN1 stats via per-block partials
__global__ __launch_bounds__(256) void k_conv1(const float* __restrict__ Y,
        const float* __restrict__ w1k, const float* __restrict__ a1w1,
        const float* __restrict__ a1b1, const float* __restrict__ a1w2,
        const float* __restrict__ a1b2,
        unsigned short* __restrict__ C1b, float* __restrict__ part1) {
    __shared__ float Ys[8 * W1];
    __shared__ float kers[128];
    __shared__ float red[4];
    int b = blockIdx.x, tid = threadIdx.x;
    const f32x4* yb4 = (const f32x4*)(Y + (size_t)b * (8 * W1));
    float psum = 0.f;
    #pragma unroll
    for (int i = 0; i < 4; ++i) {
        int idx = tid + i * 256;
        if (idx < 864) {
            f32x4 v = yb4[idx];
            *(f32x4*)&Ys[idx * 4] = v;
            psum += v[0] + v[1] + v[2] + v[3];
        }
    }
    #pragma unroll
    for (int m = 32; m; m >>= 1) psum += __shfl_xor(psum, m);
    if ((tid & 63) == 0) red[tid >> 6] = psum;
    __syncthreads();
    float p1 = (red[0] + red[1] + red[2] + red[3]) * (1.f / (8.f * W1));
    float h = fmaxf(p1 * a1w1[0] + a1b1[0], 0.f);
    float l[4], mx = -1e30f;
    #pragma unroll
    for (int k = 0; k < 4; ++k) { l[k] = (h * a1w2[k] + a1b2[k]) * (1.f / 30.f); mx = fmaxf(mx, l[k]); }
    float es = 0.f;
    #pragma unroll
    for (int k = 0; k < 4; ++k) { l[k] = expf(l[k] - mx); es += l[k]; }
    float inv = 1.f / es;
    if (tid < 128) {
        float kv = 0.f;
        #pragma unroll
        for (int k = 0; k < 4; ++k) kv += l[k] * inv * w1k[k * 128 + tid];
        kers[tid] = kv;
    }
    __syncthreads();
    int o = tid >> 4, wl = tid & 15;
    float kr[8];
    #pragma unroll
    for (int hh = 0; hh < 8; ++hh) kr[hh] = kers[o * 8 + hh];
    float ssum = 0.f, ssq = 0.f;
    unsigned short* c1b = C1b + ((size_t)b * 16 + o) * W1;
    #pragma unroll 2
    for (int j = 0; j < 13; ++j) {
        int w = 2 * wl + 32 * j;
        float a0 = 0.f, a1 = 0.f;
        #pragma unroll
        for (int hh = 0; hh < 8; ++hh) {
            float2 y2 = *(const float2*)&Ys[hh * W1 + w];
            a0 = fmaf(kr[hh], y2.x, a0);
            a1 = fmaf(kr[hh], y2.y, a1);
        }
        *(unsigned int*)&c1b[w] = bfbits(a0) | (bfbits(a1) << 16);
        ssum += a0 + a1; ssq = fmaf(a0, a0, fmaf(a1, a1, ssq));
    }
    if (wl < 8) {
        int w = 416 + 2 * wl;
        float a0 = 0.f, a1 = 0.f;
        #pragma unroll
        for (int hh = 0; hh < 8; ++hh) {
            float2 y2 = *(const float2*)&Ys[hh * W1 + w];
            a0 = fmaf(kr[hh], y2.x, a0);
            a1 = fmaf(kr[hh], y2.y, a1);
        }
        *(unsigned int*)&c1b[w] = bfbits(a0) | (bfbits(a1) << 16);
        ssum += a0 + a1; ssq = fmaf(a0, a0, fmaf(a1, a1, ssq));
    }
    #pragma unroll
    for (int m = 1; m < 16; m <<= 1) { ssum += __shfl_xor(ssum, m); ssq += __shfl_xor(ssq, m); }
    if (wl == 0) {
        part1[o * NSAMP + b] = ssum;
        part1[(16 + o) * NSAMP + b] = ssq;
    }
}

// ---------------- stats reduce + finalize: block i handles channel i
__global__ __launch_bounds__(256) void k_statfin2(const float* __restrict__ part,
        const float* __restrict__ g, const float* __restrict__ bb,
        float* __restrict__ ss, float cnt) {
    __shared__ float red[2][4];
    int i = blockIdx.x, tid = threadIdx.x;
    const f32x4* ps = (const f32x4*)(part + (size_t)i * NSAMP);
    const f32x4* qs = (const f32x4*)(part + (size_t)(16 + i) * NSAMP);
    float s = 0.f, q = 0.f;
    #pragma unroll
    for (int jj = 0; jj < 4; ++jj) {
        int j = tid + jj * 256;
        f32x4 a = ps[j], c = qs[j];
        s += a[0] + a[1] + a[2] + a[3];
        q += c[0] + c[1] + c[2] + c[3];
    }
    #pragma unroll
    for (int m = 32; m; m >>= 1) { s += __shfl_xor(s, m); q += __shfl_xor(q, m); }
    if ((tid & 63) == 0) { red[0][tid >> 6] = s; red[1][tid >> 6] = q; }
    __syncthreads();
    if (tid == 0) {
        float sum = red[0][0] + red[0][1] + red[0][2] + red[0][3];
        float sq  = red[1][0] + red[1][1] + red[1][2] + red[1][3];
        float mean = sum / cnt;
        float var  = sq / cnt - mean * mean;
        float sc = g[i] * rsqrtf(var + 1e-5f);
        ss[i] = sc;
        ss[16 + i] = bb[i] - mean * sc;
    }
}

// -------------------------------- conv2 via MFMA (BN1+relu fused, att2, stats)
#define H1T_STR 24     // shorts per row
#define H1T_ROWS 448
__global__ __launch_bounds__(256) void k_conv2(const unsigned short* __restrict__ C1b,
        const float* __restrict__ w2k, const float* __restrict__ a2w1,
        const float* __restrict__ a2b1, const float* __restrict__ a2w2,
        const float* __restrict__ a2b2, const float* __restrict__ ss,
        unsigned short* __restrict__ H2Tb, float* __restrict__ part2) {
    __shared__ __attribute__((aligned(16))) unsigned short H1T[H1T_ROWS * H1T_STR];
    __shared__ __attribute__((aligned(16))) unsigned short Bl[16 * 160];
    __shared__ float p2s[16];
    __shared__ float sred[4][2][16];
    int b = blockIdx.x, tid = threadIdx.x;
    int wv = tid >> 6, lane = tid & 63;

    int wsl = tid & 31;
    int icp = tid >> 5;
    int ic0 = icp * 2, ic1 = ic0 + 1;
    float sc0 = ss[ic0], sh0 = ss[16 + ic0], sc1 = ss[ic1], sh1 = ss[16 + ic1];
    const __bf16* cb0 = (const __bf16*)(C1b + ((size_t)b * 16 + ic0) * W1);
    const __bf16* cb1 = (const __bf16*)(C1b + ((size_t)b * 16 + ic1) * W1);
    float ps0 = 0.f, ps1 = 0.f;
    for (int w = wsl; w < W1; w += 32) {
        float v0 = fmaxf(fmaf((float)cb0[w], sc0, sh0), 0.f);
        float v1 = fmaxf(fmaf((float)cb1[w], sc1, sh1), 0.f);
        ps0 += v0; ps1 += v1;
        *(unsigned int*)&H1T[w * H1T_STR + ic0] = bfbits(v0) | (bfbits(v1) << 16);
    }
    if (tid < 128) {
        int r = 432 + (tid >> 3), c = (tid & 7) * 2;
        *(unsigned int*)&H1T[r * H1T_STR + c] = 0u;
    }
    #pragma unroll
    for (int m = 1; m < 32; m <<= 1) { ps0 += __shfl_xor(ps0, m); ps1 += __shfl_xor(ps1, m); }
    if ((lane & 31) == 0) { p2s[ic0] = ps0 * (1.f / (float)W1); p2s[ic1] = ps1 * (1.f / (float)W1); }
    __syncthreads();

    float hv[4];
    #pragma unroll
    for (int j = 0; j < 4; ++j) {
        float a = a2b1[j];
        #pragma unroll
        for (int i = 0; i < 16; ++i) a = fmaf(a2w1[j * 16 + i], p2s[i], a);
        hv[j] = fmaxf(a, 0.f);
    }
    float l[4], mx = -1e30f;
    #pragma unroll
    for (int k = 0; k < 4; ++k) {
        float a = a2b2[k];
        #pragma unroll
        for (int j = 0; j < 4; ++j) a = fmaf(a2w2[k * 4 + j], hv[j], a);
        l[k] = a * (1.f / 30.f); mx = fmaxf(mx, l[k]);
    }
    float es = 0.f;
    #pragma unroll
    for (int k = 0; k < 4; ++k) { l[k] = expf(l[k] - mx); es += l[k]; }
    float inv = 1.f / es;
    float at0 = l[0] * inv, at1 = l[1] * inv, at2 = l[2] * inv, at3 = l[3] * inv;
    for (int idx = tid; idx < 2560; idx += 256) {
        int oc = idx / 160, rem = idx - oc * 160;
        int tp = rem >> 4, ic = rem & 15;
        int so = oc * 160 + ic * 10 + tp;
        float v = at0 * w2k[so] + at1 * w2k[2560 + so] + at2 * w2k[5120 + so] + at3 * w2k[7680 + so];
        Bl[idx] = (unsigned short)bfbits(v);
    }
    __syncthreads();

    int col = lane & 15, kg = lane >> 4;
    bf16x8 bfrag[5];
    #pragma unroll
    for (int s = 0; s < 5; ++s)
        bfrag[s] = *(const bf16x8*)&Bl[col * 160 + s * 32 + kg * 8];
    float s2 = 0.f, q2 = 0.f;
    for (int mt = wv; mt < 26; mt += 4) {
        int wbase = mt * 16;
        f32x4 acc = {0.f, 0.f, 0.f, 0.f};
        #pragma unroll
        for (int s = 0; s < 5; ++s) {
            int tp = 2 * s + (kg >> 1);
            int row = wbase + col + 3 * tp;
            bf16x8 a = *(const bf16x8*)&H1T[row * H1T_STR + (kg & 1) * 8];
            acc = __builtin_amdgcn_mfma_f32_16x16x32_bf16(a, bfrag[s], acc, 0, 0, 0);
        }
        unsigned short* hb = H2Tb + (size_t)b * (16 * W2) + (wbase + kg * 4) * 16 + col;
        #pragma unroll
        for (int r = 0; r < 4; ++r) {
            int w = wbase + kg * 4 + r;
            if (w < W2) {
                float v = acc[r];
                hb[r * 16] = (unsigned short)bfbits(v);
                s2 += v; q2 = fmaf(v, v, q2);
            }
        }
    }
    s2 += __shfl_xor(s2, 16); q2 += __shfl_xor(q2, 16);
    s2 += __shfl_xor(s2, 32); q2 += __shfl_xor(q2, 32);
    if (lane < 16) { sred[wv][0][lane] = s2; sred[wv][1][lane] = q2; }
    __syncthreads();
    if (tid < 16) {
        part2[tid * NSAMP + b] = sred[0][0][tid] + sred[1][0][tid] + sred[2][0][tid] + sred[3][0][tid];
    } else if (tid < 32) {
        int i = tid - 16;
        part2[(16 + i) * NSAMP + b] = sred[0][1][i] + sred[1][1][i] + sred[2][1][i] + sred[3][1][i];
    }
}

// ----------------------------------------------------- fcw transpose (once)
__global__ void k_fcT(const float* __restrict__ fcw, float* __restrict__ fcwT) {
    int idx = blockIdx.x * 256 + threadIdx.x;
    if (idx < 4 * 16 * W2) {
        int n = idx & 3, p = idx >> 2;
        int w = p >> 4, oc = p & 15;
        fcwT[idx] = fcw[n * (16 * W2) + oc * W2 + w];
    }
}

// ------------------------------------------------------------ BN2+relu+FC out
__global__ __launch_bounds__(256) void k_fc(const unsigned short* __restrict__ H2Tb,
        const float* __restrict__ ss2, const float* __restrict__ fcwT,
        const float* __restrict__ fcb, float* __restrict__ out) {
    __shared__ float red[4][4];
    int b = blockIdx.x, tid = threadIdx.x;
    const unsigned short* hb = H2Tb + (size_t)b * (16 * W2);
    const f32x4* ft = (const f32x4*)fcwT;
    float acc[4] = {};
    for (int p = tid; p < 3240; p += 256) {
        unsigned int u = *(const unsigned int*)&hb[p * 2];
        int idx0 = p * 2;
        int oc = idx0 & 15;
        float v0 = fmaxf(fmaf(bf2f(u), ss2[oc], ss2[16 + oc]), 0.f);
        float v1 = fmaxf(fmaf(bf2f(u >> 16), ss2[oc + 1], ss2[16 + oc + 1]), 0.f);
        f32x4 w0 = ft[idx0], w1 = ft[idx0 + 1];
        #pragma unroll
        for (int n = 0; n < 4; ++n) acc[n] = fmaf(v0, w0[n], fmaf(v1, w1[n], acc[n]));
    }
    #pragma unroll
    for (int m = 1; m < 64; m <<= 1)
        #pragma unroll
        for (int n = 0; n < 4; ++n) acc[n] += __shfl_xor(acc[n], m);
    int wid = tid >> 6, lane = tid & 63;
    if (lane == 0) {
        #pragma unroll
        for (int n = 0; n < 4; ++n) red[wid][n] = acc[n];
    }
    __syncthreads();
    if (tid < 4)
        out[b * 4 + tid] = red[0][tid] + red[1][tid] + red[2][tid] + red[3][tid] + fcb[tid];
}

extern "C" void kernel_launch(void* const* d_in, const int* in_sizes, int n_in,
                              void* d_out, int out_size, void* d_ws, size_t ws_size,
                              hipStream_t stream) {
    const float* x    = (const float*)d_in[0];
    const float* w1k  = (const float*)d_in[1];
    const float* a1w1 = (const float*)d_in[2];
    const float* a1b1 = (const float*)d_in[3];
    const float* a1w2 = (const float*)d_in[4];
    const float* a1b2 = (const float*)d_in[5];
    const float* g1   = (const float*)d_in[6];
    const float* b1   = (const float*)d_in[7];
    const float* w2k  = (const float*)d_in[8];
    const float* a2w1 = (const float*)d_in[9];
    const float* a2b1 = (const float*)d_in[10];
    const float* a2w2 = (const float*)d_in[11];
    const float* a2b2 = (const float*)d_in[12];
    const float* g2   = (const float*)d_in[13];
    const float* b2   = (const float*)d_in[14];
    const float* fcw  = (const float*)d_in[15];
    const float* fcb  = (const float*)d_in[16];

    float* ws = (float*)d_ws;
    // Region Q (26,542,080 floats): Y [14,155,776 fl] then H2Tb bf16 [6,635,520 fl-equiv]
    //   part1/part2 live at Q+14,155,776 (dead space during conv phases)
    // Region P (14,155,776 floats): Xb bf16 then C1b bf16
    float*          Y    = ws;
    unsigned short* H2Tb = (unsigned short*)ws;
    float*          part1 = ws + 14155776;
    float*          part2 = part1 + 32 * NSAMP;
    unsigned short* Xb   = (unsigned short*)(ws + 26542080);
    unsigned short* C1b  = (unsigned short*)(ws + 26542080);
    unsigned short* basf = (unsigned short*)(ws + 26542080 + 14155776);
    float* ssf   = ws + 26542080 + 14155776 + 114688;
    float* fcwT  = ssf + 64;

    k_fcT<<<(4 * 16 * W2 + 255) / 256, 256, 0, stream>>>(fcw, fcwT);
    k_basis<<<112, 256, 0, stream>>>(basf);
    k_cvt<<<8192, 256, 0, stream>>>(x, Xb);
    k_dft<<<dim3(7, 256), 256, 0, stream>>>(Xb, basf, Y);
    k_conv1<<<NSAMP, 256, 0, stream>>>(Y, w1k, a1w1, a1b1, a1w2, a1b2, C1b, part1);
    k_statfin2<<<16, 256, 0, stream>>>(part1, g1, b1, ssf, 4096.f * 432.f);
    k_conv2<<<NSAMP, 256, 0, stream>>>(C1b, w2k, a2w1, a2b1, a2w2, a2b2, ssf, H2Tb, part2);
    k_statfin2<<<16, 256, 0, stream>>>(part2, g2, b2, ssf + 32, 4096.f * 405.f);
    k_fc<<<NSAMP, 256, 0, stream>>>(H2Tb, ssf + 32, fcwT, fcb, (float*)d_out);
}

// Round 5
// 156.262 us; speedup vs baseline: 8.9583x; 1.2097x over previous
//
#include <hip/hip_runtime.h>
#include <math.h>

// Problem constants
#define NB   216        // kept bins
#define W1   432        // transform width = conv1 width
#define W2   405        // conv2 output width
#define NSAMP 4096
#define NFFTC 1747

typedef __bf16 bf16x8 __attribute__((ext_vector_type(8)));
typedef float  f32x4  __attribute__((ext_vector_type(4)));
typedef unsigned int u32x4 __attribute__((ext_vector_type(4)));

__device__ __forceinline__ unsigned int bfbits(float f) {
    return (unsigned int)__builtin_bit_cast(unsigned short, (__bf16)f);
}
__device__ __forceinline__ float bf2f(unsigned int u) {
    return (float)__builtin_bit_cast(__bf16, (unsigned short)(u & 0xffff));
}
__device__ __forceinline__ void gload_lds16(const void* g, void* l) {
    __builtin_amdgcn_global_load_lds(
        (const __attribute__((address_space(1))) unsigned int*)g,
        (__attribute__((address_space(3))) unsigned int*)l, 16, 0, 0);
}

// ------------------------------------------------------- X fp32 -> bf16 packed
// Xb layout (shorts): ((rt*8+kt)*8192) + wv*2048 + mt*1024 + ks*512 + lane*8 + e
__global__ __launch_bounds__(256) void k_cvt(const float* __restrict__ x,
                                             unsigned short* __restrict__ Xb) {
    int g = blockIdx.x * 256 + threadIdx.x;      // 2,097,152 groups of 8
    int lane = g & 63;
    int t1 = g >> 6;  int ks = t1 & 1;
    int t2 = t1 >> 1; int mt = t2 & 1;
    int t3 = t2 >> 1; int wv = t3 & 3;
    int t4 = t3 >> 2; int kt = t4 & 7;
    int rt = t4 >> 3;
    int row = rt * 128 + wv * 32 + mt * 16 + (lane & 15);
    int k   = kt * 64 + ks * 32 + (lane >> 4) * 8;
    const float* src = x + (size_t)row * 512 + k;
    f32x4 a = *(const f32x4*)src;
    f32x4 b = *(const f32x4*)(src + 4);
    u32x4 v;
    v[0] = bfbits(a[0]) | (bfbits(a[1]) << 16);
    v[1] = bfbits(a[2]) | (bfbits(a[3]) << 16);
    v[2] = bfbits(b[0]) | (bfbits(b[1]) << 16);
    v[3] = bfbits(b[2]) | (bfbits(b[3]) << 16);
    *(u32x4*)(Xb + (size_t)g * 8) = v;
}

// --------------------------------------------- basis table, bf16 packed layout
__global__ __launch_bounds__(256) void k_basis(unsigned short* __restrict__ basf) {
    int g = blockIdx.x * 256 + threadIdx.x;      // 28,672 groups of 8
    int lane = g & 63;
    int t1 = g >> 6;  int ks = t1 & 1;
    int t2 = t1 >> 1; int nt = t2 & 3;
    int t3 = t2 >> 2; int kt = t3 & 7;
    int ct = t3 >> 3;
    int w  = ct * 64 + nt * 16 + (lane & 15);
    int t0 = kt * 64 + ks * 32 + (lane >> 4) * 8;
    unsigned int p[4] = {0u, 0u, 0u, 0u};
    if (w < W1) {
        int k = (w < NB) ? (24 + w) : (w - 192);
        #pragma unroll
        for (int e = 0; e < 8; ++e) {
            int m = (k * (t0 + e)) % NFFTC;
            float ang = (float)m * (float)(6.283185307179586 / 1747.0);
            float c = (w < NB) ? cosf(ang) : -sinf(ang);
            unsigned int bits = bfbits(c * (1.f / 512.f));
            p[e >> 1] |= bits << ((e & 1) * 16);
        }
    }
    u32x4 v = {p[0], p[1], p[2], p[3]};
    *(u32x4*)(basf + (size_t)g * 8) = v;
}

// ------------------------------------------------------------ DFT via MFMA
// Y (bf16) [32768][432] = X @ Basis
__global__ __launch_bounds__(256) void k_dft(const unsigned short* __restrict__ Xb,
        const unsigned short* __restrict__ basf, unsigned short* __restrict__ Yb) {
    __shared__ __attribute__((aligned(16))) unsigned short Al[8192];  // 16 KB
    __shared__ __attribute__((aligned(16))) unsigned short Bl[4096];  //  8 KB
    int ct = blockIdx.x, rt = blockIdx.y;
    int tid = threadIdx.x, wv = tid >> 6, lane = tid & 63;
    const char* asrc = (const char*)(Xb + (size_t)rt * 65536);
    const char* bsrc = (const char*)(basf + (size_t)ct * 32768);
    f32x4 acc[2][4];
    #pragma unroll
    for (int mt = 0; mt < 2; ++mt)
        #pragma unroll
        for (int nt = 0; nt < 4; ++nt) acc[mt][nt] = (f32x4){0.f, 0.f, 0.f, 0.f};

    for (int kt = 0; kt < 8; ++kt) {
        if (kt) __syncthreads();
        #pragma unroll
        for (int i = 0; i < 4; ++i)
            gload_lds16(asrc + kt * 16384 + wv * 4096 + i * 1024 + lane * 16,
                        &Al[wv * 2048 + i * 512]);
        #pragma unroll
        for (int i = 0; i < 2; ++i)
            gload_lds16(bsrc + kt * 8192 + wv * 2048 + i * 1024 + lane * 16,
                        &Bl[wv * 1024 + i * 512]);
        __syncthreads();

        bf16x8 fa[2][2], fb[4][2];
        #pragma unroll
        for (int mt = 0; mt < 2; ++mt)
            #pragma unroll
            for (int ks = 0; ks < 2; ++ks)
                fa[mt][ks] = *(const bf16x8*)&Al[wv * 2048 + mt * 1024 + ks * 512 + lane * 8];
        #pragma unroll
        for (int nt = 0; nt < 4; ++nt)
            #pragma unroll
            for (int ks = 0; ks < 2; ++ks)
                fb[nt][ks] = *(const bf16x8*)&Bl[nt * 1024 + ks * 512 + lane * 8];
        #pragma unroll
        for (int ks = 0; ks < 2; ++ks)
            #pragma unroll
            for (int mt = 0; mt < 2; ++mt)
                #pragma unroll
                for (int nt = 0; nt < 4; ++nt)
                    acc[mt][nt] = __builtin_amdgcn_mfma_f32_16x16x32_bf16(
                        fa[mt][ks], fb[nt][ks], acc[mt][nt], 0, 0, 0);
    }
    int kg = lane >> 4, col = lane & 15;
    #pragma unroll
    for (int mt = 0; mt < 2; ++mt) {
        int rbase = rt * 128 + wv * 32 + mt * 16 + kg * 4;
        #pragma unroll
        for (int nt = 0; nt < 4; ++nt) {
            int w = ct * 64 + nt * 16 + col;
            if (w < W1) {
                #pragma unroll
                for (int r = 0; r < 4; ++r)
                    Yb[(size_t)(rbase + r) * W1 + w] = (unsigned short)bfbits(acc[mt][nt][r]);
            }
        }
    }
}

// ---------------------- conv1 (+att1); out C1b [b][w][16ic] via LDS transpose
__global__ __launch_bounds__(256) void k_conv1(const unsigned short* __restrict__ Yb,
        const float* __restrict__ w1k, const float* __restrict__ a1w1,
        const float* __restrict__ a1b1, const float* __restrict__ a1w2,
        const float* __restrict__ a1b2,
        unsigned int* __restrict__ C1b32, float* __restrict__ part1) {
    __shared__ float Ys[8 * W1];                        // 13824 B
    __shared__ unsigned short C1s[W1 * 18];             // 15552 B (pad 16->18)
    __shared__ float kers[128];
    __shared__ float red[4];
    int b = blockIdx.x, tid = threadIdx.x;
    const u32x4* yb = (const u32x4*)(Yb + (size_t)b * 3456);
    float psum = 0.f;
    for (int o = tid; o < 432; o += 256) {     // 432 octets of 8 bf16
        u32x4 v = yb[o];
        float f[8];
        #pragma unroll
        for (int e = 0; e < 4; ++e) { f[2*e] = bf2f(v[e]); f[2*e+1] = bf2f(v[e] >> 16); }
        #pragma unroll
        for (int e = 0; e < 8; ++e) psum += f[e];
        *(f32x4*)&Ys[o * 8]     = (f32x4){f[0], f[1], f[2], f[3]};
        *(f32x4*)&Ys[o * 8 + 4] = (f32x4){f[4], f[5], f[6], f[7]};
    }
    #pragma unroll
    for (int m = 32; m; m >>= 1) psum += __shfl_xor(psum, m);
    if ((tid & 63) == 0) red[tid >> 6] = psum;
    __syncthreads();
    float p1 = (red[0] + red[1] + red[2] + red[3]) * (1.f / (8.f * W1));
    float h = fmaxf(p1 * a1w1[0] + a1b1[0], 0.f);
    float l[4], mx = -1e30f;
    #pragma unroll
    for (int k = 0; k < 4; ++k) { l[k] = (h * a1w2[k] + a1b2[k]) * (1.f / 30.f); mx = fmaxf(mx, l[k]); }
    float es = 0.f;
    #pragma unroll
    for (int k = 0; k < 4; ++k) { l[k] = expf(l[k] - mx); es += l[k]; }
    float inv = 1.f / es;
    if (tid < 128) {
        float kv = 0.f;
        #pragma unroll
        for (int k = 0; k < 4; ++k) kv += l[k] * inv * w1k[k * 128 + tid];
        kers[tid] = kv;
    }
    __syncthreads();
    int o = tid >> 4, wl = tid & 15;
    float kr[8];
    #pragma unroll
    for (int hh = 0; hh < 8; ++hh) kr[hh] = kers[o * 8 + hh];
    float ssum = 0.f, ssq = 0.f;
    #pragma unroll 3
    for (int j = 0; j < 27; ++j) {
        int w = wl + 16 * j;
        float acc = 0.f;
        #pragma unroll
        for (int hh = 0; hh < 8; ++hh) acc = fmaf(kr[hh], Ys[hh * W1 + w], acc);
        C1s[w * 18 + o] = (unsigned short)bfbits(acc);
        ssum += acc; ssq = fmaf(acc, acc, ssq);
    }
    #pragma unroll
    for (int m = 1; m < 16; m <<= 1) { ssum += __shfl_xor(ssum, m); ssq += __shfl_xor(ssq, m); }
    if (wl == 0) {
        part1[o * NSAMP + b] = ssum;
        part1[(16 + o) * NSAMP + b] = ssq;
    }
    __syncthreads();
    const unsigned int* C1s32 = (const unsigned int*)C1s;
    for (int m = tid; m < 3456; m += 256)      // coalesced transposed copy-out
        C1b32[(size_t)b * 3456 + m] = C1s32[(m >> 3) * 9 + (m & 7)];
}

// ---------------- stats reduce + finalize: block i handles channel i
__global__ __launch_bounds__(256) void k_statfin2(const float* __restrict__ part,
        const float* __restrict__ g, const float* __restrict__ bb,
        float* __restrict__ ss, float cnt) {
    __shared__ float red[2][4];
    int i = blockIdx.x, tid = threadIdx.x;
    const f32x4* ps = (const f32x4*)(part + (size_t)i * NSAMP);
    const f32x4* qs = (const f32x4*)(part + (size_t)(16 + i) * NSAMP);
    float s = 0.f, q = 0.f;
    #pragma unroll
    for (int jj = 0; jj < 4; ++jj) {
        int j = tid + jj * 256;
        f32x4 a = ps[j], c = qs[j];
        s += a[0] + a[1] + a[2] + a[3];
        q += c[0] + c[1] + c[2] + c[3];
    }
    #pragma unroll
    for (int m = 32; m; m >>= 1) { s += __shfl_xor(s, m); q += __shfl_xor(q, m); }
    if ((tid & 63) == 0) { red[0][tid >> 6] = s; red[1][tid >> 6] = q; }
    __syncthreads();
    if (tid == 0) {
        float sum = red[0][0] + red[0][1] + red[0][2] + red[0][3];
        float sq  = red[1][0] + red[1][1] + red[1][2] + red[1][3];
        float mean = sum / cnt;
        float var  = sq / cnt - mean * mean;
        float sc = g[i] * rsqrtf(var + 1e-5f);
        ss[i] = sc;
        ss[16 + i] = bb[i] - mean * sc;
    }
}

// ----------------------------------------------------- w2k im2col transpose
// w2kT[k][oc*160 + tp*16 + ic] = w2k[((k*16+oc)*16+ic)*10 + tp]
__global__ void k_w2kT(const float* __restrict__ w2k, float* __restrict__ w2kT) {
    int idx = blockIdx.x * 256 + threadIdx.x;
    if (idx < 10240) {
        int k = idx / 2560, rem = idx - k * 2560;
        int oc = rem / 160, r2 = rem - oc * 160;
        int tp = r2 >> 4, ic = r2 & 15;
        w2kT[idx] = w2k[((k * 16 + oc) * 16 + ic) * 10 + tp];
    }
}

// -------------------------------- conv2 via MFMA (BN1+relu fused, att2, stats)
#define H1T_STR 24     // shorts per row
#define H1T_ROWS 448
__global__ __launch_bounds__(256) void k_conv2(const unsigned short* __restrict__ C1b,
        const float* __restrict__ w2kT, const float* __restrict__ a2w1,
        const float* __restrict__ a2b1, const float* __restrict__ a2w2,
        const float* __restrict__ a2b2, const float* __restrict__ ss,
        unsigned short* __restrict__ H2Tb, float* __restrict__ part2) {
    __shared__ __attribute__((aligned(16))) unsigned short H1T[H1T_ROWS * H1T_STR];
    __shared__ __attribute__((aligned(16))) unsigned short Bl[16 * 160];
    __shared__ float p2p[4][16];
    __shared__ float sred[4][2][16];
    int b = blockIdx.x, tid = threadIdx.x;
    int wv = tid >> 6, lane = tid & 63;

    // ---- stage C1 [w][16ic] -> BN1+relu -> bf16 -> H1T rows (vectorized)
    for (int w = tid; w < W1; w += 256) {
        const u32x4* src = (const u32x4*)(C1b + ((size_t)b * W1 + w) * 16);
        u32x4 v0 = src[0], v1 = src[1];
        unsigned int op[8];
        #pragma unroll
        for (int i = 0; i < 8; ++i) {
            unsigned int u = (i < 4) ? v0[i] : v1[i - 4];
            float a = fmaxf(fmaf(bf2f(u),       ss[2*i],     ss[16 + 2*i]),     0.f);
            float c = fmaxf(fmaf(bf2f(u >> 16), ss[2*i + 1], ss[16 + 2*i + 1]), 0.f);
            op[i] = bfbits(a) | (bfbits(c) << 16);
        }
        *(u32x4*)&H1T[w * H1T_STR]     = (u32x4){op[0], op[1], op[2], op[3]};
        *(u32x4*)&H1T[w * H1T_STR + 8] = (u32x4){op[4], op[5], op[6], op[7]};
    }
    if (tid < 128) {   // zero pad rows 432..447
        int r = 432 + (tid >> 3), c = (tid & 7) * 2;
        *(unsigned int*)&H1T[r * H1T_STR + c] = 0u;
    }
    __syncthreads();

    // ---- per-channel means (conflict-free seg sums)
    {
        int ch = tid & 15, seg = tid >> 4;    // 16 segs x 27 w
        float s = 0.f;
        for (int j = 0; j < 27; ++j)
            s += bf2f((unsigned int)H1T[(seg * 27 + j) * H1T_STR + ch]);
        s += __shfl_xor(s, 16);
        s += __shfl_xor(s, 32);
        if ((lane & 48) == 0) p2p[wv][ch] = s;
    }
    __syncthreads();

    // ---- att2 (redundant per-thread, cheap)
    float hv[4];
    #pragma unroll
    for (int j = 0; j < 4; ++j) {
        float a = a2b1[j];
        #pragma unroll
        for (int i = 0; i < 16; ++i) {
            float p2 = (p2p[0][i] + p2p[1][i] + p2p[2][i] + p2p[3][i]) * (1.f / (float)W1);
            a = fmaf(a2w1[j * 16 + i], p2, a);
        }
        hv[j] = fmaxf(a, 0.f);
    }
    float l[4], mx = -1e30f;
    #pragma unroll
    for (int k = 0; k < 4; ++k) {
        float a = a2b2[k];
        #pragma unroll
        for (int j = 0; j < 4; ++j) a = fmaf(a2w2[k * 4 + j], hv[j], a);
        l[k] = a * (1.f / 30.f); mx = fmaxf(mx, l[k]);
    }
    float es = 0.f;
    #pragma unroll
    for (int k = 0; k < 4; ++k) { l[k] = expf(l[k] - mx); es += l[k]; }
    float inv = 1.f / es;
    float at0 = l[0] * inv, at1 = l[1] * inv, at2 = l[2] * inv, at3 = l[3] * inv;
    // ---- mixed kernel from pre-transposed w2kT (coalesced)
    #pragma unroll
    for (int i = 0; i < 10; ++i) {
        int idx = tid + i * 256;
        float v = at0 * w2kT[idx] + at1 * w2kT[2560 + idx]
                + at2 * w2kT[5120 + idx] + at3 * w2kT[7680 + idx];
        Bl[idx] = (unsigned short)bfbits(v);
    }
    __syncthreads();

    // ---- MFMA: 26 m-tiles of 16 w's, K=160 in 5 steps of 32
    int col = lane & 15, kg = lane >> 4;
    bf16x8 bfrag[5];
    #pragma unroll
    for (int s = 0; s < 5; ++s)
        bfrag[s] = *(const bf16x8*)&Bl[col * 160 + s * 32 + kg * 8];
    float s2 = 0.f, q2 = 0.f;
    for (int mt = wv; mt < 26; mt += 4) {
        int wbase = mt * 16;
        f32x4 acc = {0.f, 0.f, 0.f, 0.f};
        #pragma unroll
        for (int s = 0; s < 5; ++s) {
            int tp = 2 * s + (kg >> 1);
            int row = wbase + col + 3 * tp;
            bf16x8 a = *(const bf16x8*)&H1T[row * H1T_STR + (kg & 1) * 8];
            acc = __builtin_amdgcn_mfma_f32_16x16x32_bf16(a, bfrag[s], acc, 0, 0, 0);
        }
        unsigned short* hb = H2Tb + (size_t)b * (16 * W2) + (wbase + kg * 4) * 16 + col;
        #pragma unroll
        for (int r = 0; r < 4; ++r) {
            int w = wbase + kg * 4 + r;
            if (w < W2) {
                float v = acc[r];
                hb[r * 16] = (unsigned short)bfbits(v);
                s2 += v; q2 = fmaf(v, v, q2);
            }
        }
    }
    s2 += __shfl_xor(s2, 16); q2 += __shfl_xor(q2, 16);
    s2 += __shfl_xor(s2, 32); q2 += __shfl_xor(q2, 32);
    if (lane < 16) { sred[wv][0][lane] = s2; sred[wv][1][lane] = q2; }
    __syncthreads();
    if (tid < 16) {
        part2[tid * NSAMP + b] = sred[0][0][tid] + sred[1][0][tid] + sred[2][0][tid] + sred[3][0][tid];
    } else if (tid < 32) {
        int i = tid - 16;
        part2[(16 + i) * NSAMP + b] = sred[0][1][i] + sred[1][1][i] + sred[2][1][i] + sred[3][1][i];
    }
}

// --------------------------------------------- fcw -> packed bf16 pairs (once)
// pair p (elems 2p,2p+1 in [w][oc] order): fcwp[p] = u32x4 of 8 bf16
// [e0n0,e0n1 | e0n2,e0n3 | e1n0,e1n1 | e1n2,e1n3]
__global__ void k_fcT(const float* __restrict__ fcw, unsigned int* __restrict__ fcwp) {
    int p = blockIdx.x * 256 + threadIdx.x;
    if (p < 3240) {
        int idx0 = 2 * p;
        int w = idx0 >> 4, oc = idx0 & 15;
        unsigned int r[4];
        #pragma unroll
        for (int h = 0; h < 2; ++h) {
            int c = oc + h;
            float n0 = fcw[0 * 6480 + c * W2 + w];
            float n1 = fcw[1 * 6480 + c * W2 + w];
            float n2 = fcw[2 * 6480 + c * W2 + w];
            float n3 = fcw[3 * 6480 + c * W2 + w];
            r[2 * h]     = bfbits(n0) | (bfbits(n1) << 16);
            r[2 * h + 1] = bfbits(n2) | (bfbits(n3) << 16);
        }
        ((u32x4*)fcwp)[p] = (u32x4){r[0], r[1], r[2], r[3]};
    }
}

// ------------------------------------------------------------ BN2+relu+FC out
__global__ __launch_bounds__(256) void k_fc(const unsigned short* __restrict__ H2Tb,
        const float* __restrict__ ss2, const unsigned int* __restrict__ fcwp,
        const float* __restrict__ fcb, float* __restrict__ out) {
    __shared__ float red[4][4];
    int b = blockIdx.x, tid = threadIdx.x;
    const unsigned int* hb = (const unsigned int*)(H2Tb + (size_t)b * (16 * W2));
    const u32x4* fw = (const u32x4*)fcwp;
    float acc[4] = {};
    for (int p = tid; p < 3240; p += 256) {
        unsigned int u = hb[p];
        int oc = (2 * p) & 15;
        float v0 = fmaxf(fmaf(bf2f(u),       ss2[oc],     ss2[16 + oc]),     0.f);
        float v1 = fmaxf(fmaf(bf2f(u >> 16), ss2[oc + 1], ss2[16 + oc + 1]), 0.f);
        u32x4 wv4 = fw[p];
        acc[0] = fmaf(v0, bf2f(wv4[0]),       fmaf(v1, bf2f(wv4[2]),       acc[0]));
        acc[1] = fmaf(v0, bf2f(wv4[0] >> 16), fmaf(v1, bf2f(wv4[2] >> 16), acc[1]));
        acc[2] = fmaf(v0, bf2f(wv4[1]),       fmaf(v1, bf2f(wv4[3]),       acc[2]));
        acc[3] = fmaf(v0, bf2f(wv4[1] >> 16), fmaf(v1, bf2f(wv4[3] >> 16), acc[3]));
    }
    #pragma unroll
    for (int m = 1; m < 64; m <<= 1)
        #pragma unroll
        for (int n = 0; n < 4; ++n) acc[n] += __shfl_xor(acc[n], m);
    int wid = tid >> 6, lane = tid & 63;
    if (lane == 0) {
        #pragma unroll
        for (int n = 0; n < 4; ++n) red[wid][n] = acc[n];
    }
    __syncthreads();
    if (tid < 4)
        out[b * 4 + tid] = red[0][tid] + red[1][tid] + red[2][tid] + red[3][tid] + fcb[tid];
}

extern "C" void kernel_launch(void* const* d_in, const int* in_sizes, int n_in,
                              void* d_out, int out_size, void* d_ws, size_t ws_size,
                              hipStream_t stream) {
    const float* x    = (const float*)d_in[0];
    const float* w1k  = (const float*)d_in[1];
    const float* a1w1 = (const float*)d_in[2];
    const float* a1b1 = (const float*)d_in[3];
    const float* a1w2 = (const float*)d_in[4];
    const float* a1b2 = (const float*)d_in[5];
    const float* g1   = (const float*)d_in[6];
    const float* b1   = (const float*)d_in[7];
    const float* w2k  = (const float*)d_in[8];
    const float* a2w1 = (const float*)d_in[9];
    const float* a2b1 = (const float*)d_in[10];
    const float* a2w2 = (const float*)d_in[11];
    const float* a2b2 = (const float*)d_in[12];
    const float* g2   = (const float*)d_in[13];
    const float* b2   = (const float*)d_in[14];
    const float* fcw  = (const float*)d_in[15];
    const float* fcb  = (const float*)d_in[16];

    float* ws = (float*)d_ws;
    // Region Q: Yb bf16 [7,077,888 fl] then H2Tb bf16 [3,317,760 fl]
    //   part1 @ +14,155,776 ; part2 next ; w2kT / fcwp in dead zone after
    // Region P @ +26,542,080: Xb bf16 (cvt->dft) then C1b bf16 (conv1->conv2)
    unsigned short* Yb   = (unsigned short*)ws;
    unsigned short* H2Tb = (unsigned short*)ws;
    float*          part1 = ws + 14155776;
    float*          part2 = part1 + 32 * NSAMP;
    float*          w2kT  = part2 + 32 * NSAMP;          // 10240 floats
    unsigned int*   fcwp  = (unsigned int*)(w2kT + 10240); // 12960 u32
    unsigned short* Xb   = (unsigned short*)(ws + 26542080);
    unsigned short* C1b  = (unsigned short*)(ws + 26542080);
    unsigned int*   C1b32 = (unsigned int*)C1b;
    unsigned short* basf = (unsigned short*)(ws + 26542080 + 14155776);
    float* ssf   = ws + 26542080 + 14155776 + 114688;

    k_fcT<<<13, 256, 0, stream>>>(fcw, fcwp);
    k_w2kT<<<40, 256, 0, stream>>>(w2k, w2kT);
    k_basis<<<112, 256, 0, stream>>>(basf);
    k_cvt<<<8192, 256, 0, stream>>>(x, Xb);
    k_dft<<<dim3(7, 256), 256, 0, stream>>>(Xb, basf, Yb);
    k_conv1<<<NSAMP, 256, 0, stream>>>(Yb, w1k, a1w1, a1b1, a1w2, a1b2, C1b32, part1);
    k_statfin2<<<16, 256, 0, stream>>>(part1, g1, b1, ssf, 4096.f * 432.f);
    k_conv2<<<NSAMP, 256, 0, stream>>>(C1b, w2kT, a2w1, a2b1, a2w2, a2b2, ssf, H2Tb, part2);
    k_statfin2<<<16, 256, 0, stream>>>(part2, g2, b2, ssf + 32, 4096.f * 405.f);
    k_fc<<<NSAMP, 256, 0, stream>>>(H2Tb, ssf + 32, fcwp, fcb, (float*)d_out);
}

// Round 6
// 148.990 us; speedup vs baseline: 9.3955x; 1.0488x over previous
//
#include <hip/hip_runtime.h>
#include <math.h>

// Problem constants
#define NB   216        // kept bins
#define W1   432        // transform width = conv1 width
#define W2   405        // conv2 output width
#define NSAMP 4096
#define NFFTC 1747

typedef __bf16 bf16x8 __attribute__((ext_vector_type(8)));
typedef float  f32x4  __attribute__((ext_vector_type(4)));
typedef unsigned int u32x4 __attribute__((ext_vector_type(4)));
typedef unsigned short ushort_t;

__device__ __forceinline__ unsigned int bfbits(float f) {
    return (unsigned int)__builtin_bit_cast(unsigned short, (__bf16)f);
}
__device__ __forceinline__ float bf2f(unsigned int u) {
    return (float)__builtin_bit_cast(__bf16, (unsigned short)(u & 0xffff));
}
__device__ __forceinline__ void gload_lds16(const void* g, void* l) {
    __builtin_amdgcn_global_load_lds(
        (const __attribute__((address_space(1))) unsigned int*)g,
        (__attribute__((address_space(3))) unsigned int*)l, 16, 0, 0);
}

// --------------------------------------- basis table, 32-col-strip bf16 layout
// octet g: lane=g&63, ks=(g>>6)&1, nt=(g>>7)&1, kt=(g>>8)&7, st=g>>11 (0..13)
// col = st*32 + nt*16 + (lane&15) ; t = kt*64 + ks*32 + (lane>>4)*8 + e
__global__ __launch_bounds__(256) void k_basis32(unsigned short* __restrict__ basf) {
    int g = blockIdx.x * 256 + threadIdx.x;      // 28,672 octets
    int lane = g & 63;
    int ks = (g >> 6) & 1;
    int nt = (g >> 7) & 1;
    int kt = (g >> 8) & 7;
    int st = g >> 11;
    int w  = st * 32 + nt * 16 + (lane & 15);
    int t0 = kt * 64 + ks * 32 + (lane >> 4) * 8;
    unsigned int p[4] = {0u, 0u, 0u, 0u};
    if (w < W1) {
        int k = (w < NB) ? (24 + w) : (w - 192);
        #pragma unroll
        for (int e = 0; e < 8; ++e) {
            int m = (k * (t0 + e)) % NFFTC;
            float ang = (float)m * (float)(6.283185307179586 / 1747.0);
            float c = (w < NB) ? cosf(ang) : -sinf(ang);
            unsigned int bits = bfbits(c * (1.f / 512.f));
            p[e >> 1] |= bits << ((e & 1) * 16);
        }
    }
    u32x4 v = {p[0], p[1], p[2], p[3]};
    *(u32x4*)(basf + (size_t)g * 8) = v;
}

// ------------------- FUSED: X->bf16 -> DFT(MFMA, X read once) -> att1 -> conv1
// block = 32 rows (4 samples) x 448 cols ; 1024 blocks
__global__ __launch_bounds__(256, 2) void k_fused(const float* __restrict__ x,
        const unsigned short* __restrict__ basf,
        const float* __restrict__ w1k, const float* __restrict__ a1w1,
        const float* __restrict__ a1b1, const float* __restrict__ a1w2,
        const float* __restrict__ a1b2,
        unsigned short* __restrict__ C1, float* __restrict__ part1) {
    __shared__ __attribute__((aligned(16))) unsigned short Al[16384];     // 32 KB; later Ys[32][456]
    __shared__ __attribute__((aligned(16))) unsigned short Bl[2][2][2048]; // 16 KB
    int tid = threadIdx.x, blk = blockIdx.x;
    int wv = tid >> 6, lane = tid & 63;
    int rh = wv & 1, ch = wv >> 1;          // row-half, col-half
    int kg = lane >> 4, col16 = lane & 15;

#define STAGE_B(buf, ct, kt) do {                                              \
    int st_ = (ch ? 7 : 0) + (ct);                                             \
    const char* src_ = (const char*)basf +                                     \
        (size_t)(((st_ * 8 + (kt)) * 4 + rh * 2) * 64) * 16 + lane * 16;       \
    unsigned short* dst_ = &Bl[buf][ch][rh * 1024];                            \
    gload_lds16(src_, dst_);                                                   \
    gload_lds16(src_ + 1024, dst_ + 512);                                      \
} while (0)

    // prologue: B tile (0,0) in flight while we stage A
    STAGE_B(0, 0, 0);

    // ---- stage A: X fp32 -> bf16 packed fragments (read once)
    {
        int ksA = (tid >> 6) & 1, rhA = tid >> 7;
        const float* xrow = x + (size_t)(blk * 32 + rhA * 16 + (lane & 15)) * 512
                              + ksA * 32 + (lane >> 4) * 8;
        #pragma unroll
        for (int i = 0; i < 8; ++i) {
            f32x4 a = *(const f32x4*)(xrow + i * 64);
            f32x4 b = *(const f32x4*)(xrow + i * 64 + 4);
            u32x4 v;
            v[0] = bfbits(a[0]) | (bfbits(a[1]) << 16);
            v[1] = bfbits(a[2]) | (bfbits(a[3]) << 16);
            v[2] = bfbits(b[0]) | (bfbits(b[1]) << 16);
            v[3] = bfbits(b[2]) | (bfbits(b[3]) << 16);
            *(u32x4*)&Al[(size_t)(tid + 256 * i) * 8] = v;
        }
    }
    __syncthreads();   // A ds_writes + B dma drained

    // ---- hoist all A fragments to registers (Al becomes dead after this)
    bf16x8 fa[8][2];
    #pragma unroll
    for (int kt = 0; kt < 8; ++kt)
        #pragma unroll
        for (int ks = 0; ks < 2; ++ks)
            fa[kt][ks] = *(const bf16x8*)&Al[(((kt * 2 + rh) * 2 + ks) * 64 + lane) * 8];

    // ---- main loop: 7 ct x 8 kt, 2-phase staged B, acc fully in regs
    f32x4 acc[14];
    #pragma unroll
    for (int i = 0; i < 14; ++i) acc[i] = (f32x4){0.f, 0.f, 0.f, 0.f};

    #pragma unroll
    for (int ct = 0; ct < 7; ++ct) {
        #pragma unroll
        for (int kt = 0; kt < 8; ++kt) {
            const int t = ct * 8 + kt;
            const int buf = t & 1;
            if (t + 1 < 56) {
                const int nct = (t + 1) >> 3, nkt = (t + 1) & 7;
                STAGE_B(buf ^ 1, nct, nkt);
            }
            #pragma unroll
            for (int nt = 0; nt < 2; ++nt)
                #pragma unroll
                for (int ks = 0; ks < 2; ++ks) {
                    bf16x8 fb = *(const bf16x8*)&Bl[buf][ch][(nt * 2 + ks) * 512 + lane * 8];
                    acc[ct * 2 + nt] = __builtin_amdgcn_mfma_f32_16x16x32_bf16(
                        fa[kt][ks], fb, acc[ct * 2 + nt], 0, 0, 0);
                }
            __syncthreads();
        }
    }

    // ---- write Y (bf16) into reused Al region: Ys[32 rows][456]
    unsigned short* Ys = Al;
    #pragma unroll
    for (int ct = 0; ct < 7; ++ct)
        #pragma unroll
        for (int nt = 0; nt < 2; ++nt) {
            int col = ch * 224 + ct * 32 + nt * 16 + col16;
            #pragma unroll
            for (int e = 0; e < 4; ++e) {
                int row = rh * 16 + kg * 4 + e;
                Ys[row * 456 + col] = (unsigned short)bfbits(acc[ct * 2 + nt][e]);
            }
        }
    __syncthreads();

    // ---- fused conv1: wave wv handles sample s = wv
    int s = wv;
    float psum = 0.f;
    #pragma unroll
    for (int jj = 0; jj < 54; ++jj) {
        int idx = lane + 64 * jj;              // 0..3455 over [8ch][432w]
        int ch8 = idx / 432;
        int w = idx - ch8 * 432;
        psum += bf2f((unsigned int)Ys[(s * 8 + ch8) * 456 + w]);
    }
    #pragma unroll
    for (int m = 1; m < 64; m <<= 1) psum += __shfl_xor(psum, m);
    float p1 = psum * (1.f / (8.f * W1));
    float h = fmaxf(p1 * a1w1[0] + a1b1[0], 0.f);
    float l[4], mx = -1e30f;
    #pragma unroll
    for (int k = 0; k < 4; ++k) { l[k] = (h * a1w2[k] + a1b2[k]) * (1.f / 30.f); mx = fmaxf(mx, l[k]); }
    float es = 0.f;
    #pragma unroll
    for (int k = 0; k < 4; ++k) { l[k] = expf(l[k] - mx); es += l[k]; }
    float inv = 1.f / es;
    float at[4] = {l[0] * inv, l[1] * inv, l[2] * inv, l[3] * inv};

    int o = lane & 15, wl = lane >> 4;
    float kr[8];
    #pragma unroll
    for (int hh = 0; hh < 8; ++hh) {
        float kv = 0.f;
        #pragma unroll
        for (int k = 0; k < 4; ++k) kv = fmaf(at[k], w1k[k * 128 + o * 8 + hh], kv);
        kr[hh] = kv;
    }
    int b = blk * 4 + s;
    unsigned short* c1o = C1 + (size_t)b * (432 * 16);
    float ssum = 0.f, ssq = 0.f;
    for (int j = 0; j < 108; ++j) {
        int w = 4 * j + wl;
        float a = 0.f;
        #pragma unroll
        for (int hh = 0; hh < 8; ++hh)
            a = fmaf(kr[hh], bf2f((unsigned int)Ys[(s * 8 + hh) * 456 + w]), a);
        c1o[w * 16 + o] = (unsigned short)bfbits(a);
        ssum += a; ssq = fmaf(a, a, ssq);
    }
    ssum += __shfl_xor(ssum, 16); ssq += __shfl_xor(ssq, 16);
    ssum += __shfl_xor(ssum, 32); ssq += __shfl_xor(ssq, 32);
    if (lane < 16) {
        part1[lane * NSAMP + b] = ssum;
        part1[(16 + lane) * NSAMP + b] = ssq;
    }
#undef STAGE_B
}

// ---------------- stats reduce + finalize: block i handles channel i
__global__ __launch_bounds__(256) void k_statfin2(const float* __restrict__ part,
        const float* __restrict__ g, const float* __restrict__ bb,
        float* __restrict__ ss, float cnt) {
    __shared__ float red[2][4];
    int i = blockIdx.x, tid = threadIdx.x;
    const f32x4* ps = (const f32x4*)(part + (size_t)i * NSAMP);
    const f32x4* qs = (const f32x4*)(part + (size_t)(16 + i) * NSAMP);
    float s = 0.f, q = 0.f;
    #pragma unroll
    for (int jj = 0; jj < 4; ++jj) {
        int j = tid + jj * 256;
        f32x4 a = ps[j], c = qs[j];
        s += a[0] + a[1] + a[2] + a[3];
        q += c[0] + c[1] + c[2] + c[3];
    }
    #pragma unroll
    for (int m = 32; m; m >>= 1) { s += __shfl_xor(s, m); q += __shfl_xor(q, m); }
    if ((tid & 63) == 0) { red[0][tid >> 6] = s; red[1][tid >> 6] = q; }
    __syncthreads();
    if (tid == 0) {
        float sum = red[0][0] + red[0][1] + red[0][2] + red[0][3];
        float sq  = red[1][0] + red[1][1] + red[1][2] + red[1][3];
        float mean = sum / cnt;
        float var  = sq / cnt - mean * mean;
        float sc = g[i] * rsqrtf(var + 1e-5f);
        ss[i] = sc;
        ss[16 + i] = bb[i] - mean * sc;
    }
}

// ----------------------------------------------------- w2k im2col transpose
__global__ void k_w2kT(const float* __restrict__ w2k, float* __restrict__ w2kT) {
    int idx = blockIdx.x * 256 + threadIdx.x;
    if (idx < 10240) {
        int k = idx / 2560, rem = idx - k * 2560;
        int oc = rem / 160, r2 = rem - oc * 160;
        int tp = r2 >> 4, ic = r2 & 15;
        w2kT[idx] = w2k[((k * 16 + oc) * 16 + ic) * 10 + tp];
    }
}

// -------------------------------- conv2 via MFMA (BN1+relu fused, att2, stats)
#define H1T_STR 24     // shorts per row
#define H1T_ROWS 448
__global__ __launch_bounds__(256) void k_conv2(const unsigned short* __restrict__ C1b,
        const float* __restrict__ w2kT, const float* __restrict__ a2w1,
        const float* __restrict__ a2b1, const float* __restrict__ a2w2,
        const float* __restrict__ a2b2, const float* __restrict__ ss,
        unsigned short* __restrict__ H2Tb, float* __restrict__ part2) {
    __shared__ __attribute__((aligned(16))) unsigned short H1T[H1T_ROWS * H1T_STR];
    __shared__ __attribute__((aligned(16))) unsigned short Bl[16 * 160];
    __shared__ float p2p[4][16];
    __shared__ float sred[4][2][16];
    int b = blockIdx.x, tid = threadIdx.x;
    int wv = tid >> 6, lane = tid & 63;

    // ---- stage C1 [w][16ic] -> BN1+relu -> bf16 -> H1T rows (vectorized)
    for (int w = tid; w < W1; w += 256) {
        const u32x4* src = (const u32x4*)(C1b + ((size_t)b * W1 + w) * 16);
        u32x4 v0 = src[0], v1 = src[1];
        unsigned int op[8];
        #pragma unroll
        for (int i = 0; i < 8; ++i) {
            unsigned int u = (i < 4) ? v0[i] : v1[i - 4];
            float a = fmaxf(fmaf(bf2f(u),       ss[2*i],     ss[16 + 2*i]),     0.f);
            float c = fmaxf(fmaf(bf2f(u >> 16), ss[2*i + 1], ss[16 + 2*i + 1]), 0.f);
            op[i] = bfbits(a) | (bfbits(c) << 16);
        }
        *(u32x4*)&H1T[w * H1T_STR]     = (u32x4){op[0], op[1], op[2], op[3]};
        *(u32x4*)&H1T[w * H1T_STR + 8] = (u32x4){op[4], op[5], op[6], op[7]};
    }
    if (tid < 128) {   // zero pad rows 432..447
        int r = 432 + (tid >> 3), c = (tid & 7) * 2;
        *(unsigned int*)&H1T[r * H1T_STR + c] = 0u;
    }
    __syncthreads();

    // ---- per-channel means (conflict-free seg sums)
    {
        int chn = tid & 15, seg = tid >> 4;    // 16 segs x 27 w
        float s = 0.f;
        for (int j = 0; j < 27; ++j)
            s += bf2f((unsigned int)H1T[(seg * 27 + j) * H1T_STR + chn]);
        s += __shfl_xor(s, 16);
        s += __shfl_xor(s, 32);
        if ((lane & 48) == 0) p2p[wv][chn] = s;
    }
    __syncthreads();

    // ---- att2 (redundant per-thread, cheap)
    float hv[4];
    #pragma unroll
    for (int j = 0; j < 4; ++j) {
        float a = a2b1[j];
        #pragma unroll
        for (int i = 0; i < 16; ++i) {
            float p2 = (p2p[0][i] + p2p[1][i] + p2p[2][i] + p2p[3][i]) * (1.f / (float)W1);
            a = fmaf(a2w1[j * 16 + i], p2, a);
        }
        hv[j] = fmaxf(a, 0.f);
    }
    float l[4], mx = -1e30f;
    #pragma unroll
    for (int k = 0; k < 4; ++k) {
        float a = a2b2[k];
        #pragma unroll
        for (int j = 0; j < 4; ++j) a = fmaf(a2w2[k * 4 + j], hv[j], a);
        l[k] = a * (1.f / 30.f); mx = fmaxf(mx, l[k]);
    }
    float es = 0.f;
    #pragma unroll
    for (int k = 0; k < 4; ++k) { l[k] = expf(l[k] - mx); es += l[k]; }
    float inv = 1.f / es;
    float at0 = l[0] * inv, at1 = l[1] * inv, at2 = l[2] * inv, at3 = l[3] * inv;
    // ---- mixed kernel from pre-transposed w2kT (coalesced)
    #pragma unroll
    for (int i = 0; i < 10; ++i) {
        int idx = tid + i * 256;
        float v = at0 * w2kT[idx] + at1 * w2kT[2560 + idx]
                + at2 * w2kT[5120 + idx] + at3 * w2kT[7680 + idx];
        Bl[idx] = (unsigned short)bfbits(v);
    }
    __syncthreads();

    // ---- MFMA: 26 m-tiles of 16 w's, K=160 in 5 steps of 32
    int col = lane & 15, kg = lane >> 4;
    bf16x8 bfrag[5];
    #pragma unroll
    for (int s = 0; s < 5; ++s)
        bfrag[s] = *(const bf16x8*)&Bl[col * 160 + s * 32 + kg * 8];
    float s2 = 0.f, q2 = 0.f;
    for (int mt = wv; mt < 26; mt += 4) {
        int wbase = mt * 16;
        f32x4 acc = {0.f, 0.f, 0.f, 0.f};
        #pragma unroll
        for (int s = 0; s < 5; ++s) {
            int tp = 2 * s + (kg >> 1);
            int row = wbase + col + 3 * tp;
            bf16x8 a = *(const bf16x8*)&H1T[row * H1T_STR + (kg & 1) * 8];
            acc = __builtin_amdgcn_mfma_f32_16x16x32_bf16(a, bfrag[s], acc, 0, 0, 0);
        }
        unsigned short* hb = H2Tb + (size_t)b * (16 * W2) + (wbase + kg * 4) * 16 + col;
        #pragma unroll
        for (int r = 0; r < 4; ++r) {
            int w = wbase + kg * 4 + r;
            if (w < W2) {
                float v = acc[r];
                hb[r * 16] = (unsigned short)bfbits(v);
                s2 += v; q2 = fmaf(v, v, q2);
            }
        }
    }
    s2 += __shfl_xor(s2, 16); q2 += __shfl_xor(q2, 16);
    s2 += __shfl_xor(s2, 32); q2 += __shfl_xor(q2, 32);
    if (lane < 16) { sred[wv][0][lane] = s2; sred[wv][1][lane] = q2; }
    __syncthreads();
    if (tid < 16) {
        part2[tid * NSAMP + b] = sred[0][0][tid] + sred[1][0][tid] + sred[2][0][tid] + sred[3][0][tid];
    } else if (tid < 32) {
        int i = tid - 16;
        part2[(16 + i) * NSAMP + b] = sred[0][1][i] + sred[1][1][i] + sred[2][1][i] + sred[3][1][i];
    }
}

// --------------------------------------------- fcw -> packed bf16 pairs (once)
__global__ void k_fcT(const float* __restrict__ fcw, unsigned int* __restrict__ fcwp) {
    int p = blockIdx.x * 256 + threadIdx.x;
    if (p < 3240) {
        int idx0 = 2 * p;
        int w = idx0 >> 4, oc = idx0 & 15;
        unsigned int r[4];
        #pragma unroll
        for (int h = 0; h < 2; ++h) {
            int c = oc + h;
            float n0 = fcw[0 * 6480 + c * W2 + w];
            float n1 = fcw[1 * 6480 + c * W2 + w];
            float n2 = fcw[2 * 6480 + c * W2 + w];
            float n3 = fcw[3 * 6480 + c * W2 + w];
            r[2 * h]     = bfbits(n0) | (bfbits(n1) << 16);
            r[2 * h + 1] = bfbits(n2) | (bfbits(n3) << 16);
        }
        ((u32x4*)fcwp)[p] = (u32x4){r[0], r[1], r[2], r[3]};
    }
}

// ------------------------------------------------------------ BN2+relu+FC out
__global__ __launch_bounds__(256) void k_fc(const unsigned short* __restrict__ H2Tb,
        const float* __restrict__ ss2, const unsigned int* __restrict__ fcwp,
        const float* __restrict__ fcb, float* __restrict__ out) {
    __shared__ float red[4][4];
    int b = blockIdx.x, tid = threadIdx.x;
    const unsigned int* hb = (const unsigned int*)(H2Tb + (size_t)b * (16 * W2));
    const u32x4* fw = (const u32x4*)fcwp;
    float acc[4] = {};
    for (int p = tid; p < 3240; p += 256) {
        unsigned int u = hb[p];
        int oc = (2 * p) & 15;
        float v0 = fmaxf(fmaf(bf2f(u),       ss2[oc],     ss2[16 + oc]),     0.f);
        float v1 = fmaxf(fmaf(bf2f(u >> 16), ss2[oc + 1], ss2[16 + oc + 1]), 0.f);
        u32x4 wv4 = fw[p];
        acc[0] = fmaf(v0, bf2f(wv4[0]),       fmaf(v1, bf2f(wv4[2]),       acc[0]));
        acc[1] = fmaf(v0, bf2f(wv4[0] >> 16), fmaf(v1, bf2f(wv4[2] >> 16), acc[1]));
        acc[2] = fmaf(v0, bf2f(wv4[1]),       fmaf(v1, bf2f(wv4[3]),       acc[2]));
        acc[3] = fmaf(v0, bf2f(wv4[1] >> 16), fmaf(v1, bf2f(wv4[3] >> 16), acc[3]));
    }
    #pragma unroll
    for (int m = 1; m < 64; m <<= 1)
        #pragma unroll
        for (int n = 0; n < 4; ++n) acc[n] += __shfl_xor(acc[n], m);
    int wid = tid >> 6, lane = tid & 63;
    if (lane == 0) {
        #pragma unroll
        for (int n = 0; n < 4; ++n) red[wid][n] = acc[n];
    }
    __syncthreads();
    if (tid < 4)
        out[b * 4 + tid] = red[0][tid] + red[1][tid] + red[2][tid] + red[3][tid] + fcb[tid];
}

extern "C" void kernel_launch(void* const* d_in, const int* in_sizes, int n_in,
                              void* d_out, int out_size, void* d_ws, size_t ws_size,
                              hipStream_t stream) {
    const float* x    = (const float*)d_in[0];
    const float* w1k  = (const float*)d_in[1];
    const float* a1w1 = (const float*)d_in[2];
    const float* a1b1 = (const float*)d_in[3];
    const float* a1w2 = (const float*)d_in[4];
    const float* a1b2 = (const float*)d_in[5];
    const float* g1   = (const float*)d_in[6];
    const float* b1   = (const float*)d_in[7];
    const float* w2k  = (const float*)d_in[8];
    const float* a2w1 = (const float*)d_in[9];
    const float* a2b1 = (const float*)d_in[10];
    const float* a2w2 = (const float*)d_in[11];
    const float* a2b2 = (const float*)d_in[12];
    const float* g2   = (const float*)d_in[13];
    const float* b2   = (const float*)d_in[14];
    const float* fcw  = (const float*)d_in[15];
    const float* fcb  = (const float*)d_in[16];

    float* ws = (float*)d_ws;
    // Region Q: H2Tb bf16 [3,317,760 fl-equiv] ; part1/part2 @ +14,155,776
    // Region P @ +26,542,080: C1b bf16 [b][w][16oc]
    unsigned short* H2Tb = (unsigned short*)ws;
    float*          part1 = ws + 14155776;
    float*          part2 = part1 + 32 * NSAMP;
    float*          w2kT  = part2 + 32 * NSAMP;            // 10240 floats
    unsigned int*   fcwp  = (unsigned int*)(w2kT + 10240); // 12960 u32
    unsigned short* C1b  = (unsigned short*)(ws + 26542080);
    unsigned short* basf = (unsigned short*)(ws + 26542080 + 14155776);
    float* ssf   = ws + 26542080 + 14155776 + 114688;

    k_fcT<<<13, 256, 0, stream>>>(fcw, fcwp);
    k_w2kT<<<40, 256, 0, stream>>>(w2k, w2kT);
    k_basis32<<<112, 256, 0, stream>>>(basf);
    k_fused<<<1024, 256, 0, stream>>>(x, basf, w1k, a1w1, a1b1, a1w2, a1b2, C1b, part1);
    k_statfin2<<<16, 256, 0, stream>>>(part1, g1, b1, ssf, 4096.f * 432.f);
    k_conv2<<<NSAMP, 256, 0, stream>>>(C1b, w2kT, a2w1, a2b1, a2w2, a2b2, ssf, H2Tb, part2);
    k_statfin2<<<16, 256, 0, stream>>>(part2, g2, b2, ssf + 32, 4096.f * 405.f);
    k_fc<<<NSAMP, 256, 0, stream>>>(H2Tb, ssf + 32, fcwp, fcb, (float*)d_out);
}